// Round 1
// 1376.384 us; speedup vs baseline: 1.2261x; 1.2261x over previous
//
#include <hip/hip_runtime.h>
#include <hip/hip_bf16.h>

// Problem constants: B=2, S=2048, D=1024, H=16, HD=64, E=4, K=2, HID=4096, T=4096
#define T_TOK 4096
#define DIM   1024
#define NHEAD 16
#define HDIM  64
#define SEQ   2048
#define NEXP  4
#define HIDD  4096
#define QS    66   // attention LDS row stride (shorts)

typedef short bf16x8 __attribute__((ext_vector_type(8)));
typedef float f32x4  __attribute__((ext_vector_type(4)));

enum { GF_GELU = 1, GF_RESID = 2, GF_SCALE = 4, GF_ACCUM = 8 };

__device__ inline unsigned short f2bf(float f) {
  union { float f; unsigned u; } v; v.f = f;
  unsigned r = v.u + 0x7FFFu + ((v.u >> 16) & 1u);
  return (unsigned short)(r >> 16);
}
__device__ inline int pack2(float a, float b) {
  return (int)((unsigned)f2bf(a) | ((unsigned)f2bf(b) << 16));
}
__device__ inline float gelu_f(float x) {
  const float c = 0.7978845608028654f;
  float t = tanhf(c * (x + 0.044715f * x * x * x));
  return 0.5f * x * (1.0f + t);
}
__device__ inline void gld_lds16(const unsigned short* g, unsigned short* l) {
  __builtin_amdgcn_global_load_lds(
      (const __attribute__((address_space(1))) void*)g,
      (__attribute__((address_space(3))) void*)l, 16, 0, 0);
}

// ---------------------------------------------------------------------------
__global__ __launch_bounds__(256) void cvt_kernel(
    const float* __restrict__ in, unsigned short* __restrict__ out, int n8)
{
  int i = blockIdx.x * 256 + threadIdx.x;
  if (i >= n8) return;
  const float4* p = (const float4*)in + (size_t)i * 2;
  float4 v0 = p[0], v1 = p[1];
  int4 pk = make_int4(pack2(v0.x, v0.y), pack2(v0.z, v0.w),
                      pack2(v1.x, v1.y), pack2(v1.z, v1.w));
  *(int4*)(out + (size_t)i * 8) = pk;
}

// ---------------------------------------------------------------------------
// m97-style bf16 GEMM: C = A @ W^T (+epilogue). 128x128 tile, BK=32, 256 thr.
// Optional split-K via gridDim.z (z=0 -> C, z=1 -> Cz; both pre-initialized).
// ---------------------------------------------------------------------------
__global__ __launch_bounds__(256) void gemm_bf16(
    const unsigned short* __restrict__ A, const unsigned short* __restrict__ W,
    const float* __restrict__ bias, const float* __restrict__ resid,
    const float* __restrict__ scale, float* __restrict__ C,
    float* __restrict__ Cz, unsigned short* __restrict__ C2,
    int M, int N, int Kd, int flags)
{
  __shared__ __align__(16) unsigned short As[128 * 32];
  __shared__ __align__(16) unsigned short Bs[128 * 32];

  const int tid  = threadIdx.x;
  const int wave = tid >> 6, lane = tid & 63;
  const int bm = blockIdx.y, bn = blockIdx.x;
  const int kz = blockIdx.z;
  const int kseg = Kd / gridDim.z;       // K-range for this z-slice
  if (kz == 1) C = Cz;

  const int srow = lane >> 2;            // 0..15
  const int scol = (lane & 3) << 3;      // 0,8,16,24 (bf16 elems)
  const unsigned short* Ag = A + (size_t)(bm * 128 + wave * 32 + srow) * Kd + scol + (size_t)kz * kseg;
  const unsigned short* Wg = W + (size_t)(bn * 128 + wave * 32 + srow) * Kd + scol + (size_t)kz * kseg;
  unsigned short* AsBase = As + wave * 32 * 32;
  unsigned short* BsBase = Bs + wave * 32 * 32;

  const int wm = wave >> 1, wn = wave & 1;
  const int fr = lane & 15;
  const int fq = lane >> 4;

  f32x4 acc[4][4] = {};

  for (int k0 = 0; k0 < kseg; k0 += 32) {
    __syncthreads();
    gld_lds16(Ag + k0,            AsBase);
    gld_lds16(Ag + k0 + 16 * Kd,  AsBase + 16 * 32);
    gld_lds16(Wg + k0,            BsBase);
    gld_lds16(Wg + k0 + 16 * Kd,  BsBase + 16 * 32);
    __syncthreads();
    bf16x8 a[4], b[4];
#pragma unroll
    for (int i = 0; i < 4; ++i) {
      a[i] = *(const bf16x8*)&As[(wm * 64 + i * 16 + fr) * 32 + fq * 8];
      b[i] = *(const bf16x8*)&Bs[(wn * 64 + i * 16 + fr) * 32 + fq * 8];
    }
#pragma unroll
    for (int mt = 0; mt < 4; ++mt)
#pragma unroll
      for (int nt = 0; nt < 4; ++nt)
        acc[mt][nt] = __builtin_amdgcn_mfma_f32_16x16x32_bf16(a[mt], b[nt], acc[mt][nt], 0, 0, 0);
  }

#pragma unroll
  for (int mt = 0; mt < 4; ++mt)
#pragma unroll
    for (int nt = 0; nt < 4; ++nt)
#pragma unroll
      for (int r = 0; r < 4; ++r) {
        int row = bm * 128 + wm * 64 + mt * 16 + fq * 4 + r;
        int col = bn * 128 + wn * 64 + nt * 16 + fr;
        float v = acc[mt][nt][r];
        if (bias) v += bias[col];
        if (flags & GF_GELU) v = gelu_f(v);
        if (flags & GF_RESID) v += resid[(size_t)row * N + col];
        if (flags & GF_SCALE) v *= scale[row];
        size_t idx = (size_t)row * N + col;
        if (C) { if (flags & GF_ACCUM) C[idx] += v; else C[idx] = v; }
        if (C2) C2[idx] = f2bf(v);
      }
}

// ---------------------------------------------------------------------------
// bf16 MFMA flash attention, causal, paired Q-tiles. Grid (16, B*H), 256 thr.
// Per wave: 16 Q-rows. S via 8 QK^T MFMAs; online softmax in registers
// (quad-shuffles); P roundtrip via wave-private LDS; PV via 8 MFMAs with V^T.
// ---------------------------------------------------------------------------
__global__ __launch_bounds__(256) void attn_mfma(
    const unsigned short* __restrict__ qkv, unsigned short* __restrict__ o)
{
  __shared__ __align__(16) unsigned short Qs[64 * QS];
  __shared__ __align__(16) unsigned short Ks[64 * QS];
  __shared__ __align__(16) unsigned short Vt[64 * QS];  // transposed: Vt[d][k]
  __shared__ __align__(16) unsigned short Ps[64 * QS];  // wave-private 16-row bands

  const int tid  = threadIdx.x;
  const int wave = tid >> 6, lane = tid & 63;
  const int quad = lane >> 4, l15 = lane & 15;
  const int bh = blockIdx.y, b = bh >> 4, h = bh & 15;

  const int srow = tid >> 2;            // staging row 0..63
  const int scol = (tid & 3) << 4;      // staging col base (16 shorts)

  for (int half = 0; half < 2; ++half) {
    const int qb = half ? (31 - (int)blockIdx.x) : (int)blockIdx.x;
    const int q0 = qb << 6;

    __syncthreads();  // prior half fully done before overwriting Qs
    {
      const unsigned short* qp = qkv + ((size_t)(b * SEQ + q0 + srow)) * 3072 + h * 64 + scol;
      *(int4*)&Qs[srow * QS + scol]     = *(const int4*)qp;
      *(int4*)&Qs[srow * QS + scol + 8] = *(const int4*)(qp + 8);
    }
    __syncthreads();
    bf16x8 qf0 = *(const bf16x8*)&Qs[(wave * 16 + l15) * QS + quad * 8];
    bf16x8 qf1 = *(const bf16x8*)&Qs[(wave * 16 + l15) * QS + 32 + quad * 8];

    f32x4 Oc[4] = {};
    float mr[4] = {-1e30f, -1e30f, -1e30f, -1e30f};
    float ls[4] = {0.f, 0.f, 0.f, 0.f};

    for (int kt = 0; kt <= qb; ++kt) {
      __syncthreads();  // previous iteration's K/Vt reads complete
      {
        const unsigned short* kp = qkv + ((size_t)(b * SEQ + (kt << 6) + srow)) * 3072 + 1024 + h * 64 + scol;
        const unsigned short* vp = kp + 1024;
        *(int4*)&Ks[srow * QS + scol]     = *(const int4*)kp;
        *(int4*)&Ks[srow * QS + scol + 8] = *(const int4*)(kp + 8);
        unsigned short vs[16];
        *(int4*)&vs[0] = *(const int4*)vp;
        *(int4*)&vs[8] = *(const int4*)(vp + 8);
#pragma unroll
        for (int i = 0; i < 16; ++i)
          Vt[(scol + i) * QS + srow] = vs[i];
      }
      __syncthreads();

      // S = Q K^T  (per wave: 16 rows x 64 cols = 4 col-tiles)
      f32x4 sc[4] = {};
#pragma unroll
      for (int ct = 0; ct < 4; ++ct) {
        bf16x8 k0 = *(const bf16x8*)&Ks[(ct * 16 + l15) * QS + quad * 8];
        bf16x8 k1 = *(const bf16x8*)&Ks[(ct * 16 + l15) * QS + 32 + quad * 8];
        sc[ct] = __builtin_amdgcn_mfma_f32_16x16x32_bf16(qf0, k0, sc[ct], 0, 0, 0);
        sc[ct] = __builtin_amdgcn_mfma_f32_16x16x32_bf16(qf1, k1, sc[ct], 0, 0, 0);
      }

      // scale + causal mask (C-layout: local col = ct*16+l15,
      // local row within tile = wave*16 + quad*4 + r  — wave offset REQUIRED)
      float sv[4][4];
      const bool diag = (kt == qb);
#pragma unroll
      for (int ct = 0; ct < 4; ++ct)
#pragma unroll
        for (int r = 0; r < 4; ++r) {
          float v = sc[ct][r] * 0.125f;
          if (diag && (ct * 16 + l15) > (wave * 16 + quad * 4 + r)) v = -1e9f;
          sv[ct][r] = v;
        }
      // row stats (rows live in one 16-lane group)
      float rm[4], rs[4];
#pragma unroll
      for (int r = 0; r < 4; ++r)
        rm[r] = fmaxf(fmaxf(sv[0][r], sv[1][r]), fmaxf(sv[2][r], sv[3][r]));
#pragma unroll
      for (int m = 1; m < 16; m <<= 1)
#pragma unroll
        for (int r = 0; r < 4; ++r) rm[r] = fmaxf(rm[r], __shfl_xor(rm[r], m, 16));
      float al[4];
#pragma unroll
      for (int r = 0; r < 4; ++r) {
        float nm = fmaxf(mr[r], rm[r]);
        al[r] = __expf(mr[r] - nm);
        mr[r] = nm;
        rs[r] = 0.f;
      }
#pragma unroll
      for (int ct = 0; ct < 4; ++ct)
#pragma unroll
        for (int r = 0; r < 4; ++r) {
          float p = __expf(sv[ct][r] - mr[r]);
          sv[ct][r] = p;
          rs[r] += p;
        }
#pragma unroll
      for (int m = 1; m < 16; m <<= 1)
#pragma unroll
        for (int r = 0; r < 4; ++r) rs[r] += __shfl_xor(rs[r], m, 16);
#pragma unroll
      for (int r = 0; r < 4; ++r) {
        ls[r] = ls[r] * al[r] + rs[r];
        for (int ct = 0; ct < 4; ++ct) Oc[ct][r] *= al[r];
      }
      // P -> LDS (wave-private band, no barrier needed)
#pragma unroll
      for (int ct = 0; ct < 4; ++ct)
#pragma unroll
        for (int r = 0; r < 4; ++r)
          Ps[(wave * 16 + quad * 4 + r) * QS + ct * 16 + l15] = f2bf(sv[ct][r]);
      // PV
      bf16x8 pf0 = *(const bf16x8*)&Ps[(wave * 16 + l15) * QS + quad * 8];
      bf16x8 pf1 = *(const bf16x8*)&Ps[(wave * 16 + l15) * QS + 32 + quad * 8];
#pragma unroll
      for (int ct = 0; ct < 4; ++ct) {
        bf16x8 v0 = *(const bf16x8*)&Vt[(ct * 16 + l15) * QS + quad * 8];
        bf16x8 v1 = *(const bf16x8*)&Vt[(ct * 16 + l15) * QS + 32 + quad * 8];
        Oc[ct] = __builtin_amdgcn_mfma_f32_16x16x32_bf16(pf0, v0, Oc[ct], 0, 0, 0);
        Oc[ct] = __builtin_amdgcn_mfma_f32_16x16x32_bf16(pf1, v1, Oc[ct], 0, 0, 0);
      }
    }

#pragma unroll
    for (int r = 0; r < 4; ++r) {
      float inv = 1.0f / ls[r];
      unsigned short* orow = o + ((size_t)(b * SEQ + q0 + wave * 16 + quad * 4 + r)) * DIM + h * 64;
#pragma unroll
      for (int ct = 0; ct < 4; ++ct)
        orow[ct * 16 + l15] = f2bf(Oc[ct][r] * inv);
    }
  }
}

// ---------------------------------------------------------------------------
__global__ __launch_bounds__(256) void ln_kernel(
    const float* __restrict__ x, const float* __restrict__ g,
    const float* __restrict__ b, unsigned short* __restrict__ out)
{
  const int t = blockIdx.x, tid = threadIdx.x;
  const float* row = x + (size_t)t * DIM;
  float4 v = *(const float4*)(row + tid * 4);
  float s  = v.x + v.y + v.z + v.w;
  float s2 = v.x * v.x + v.y * v.y + v.z * v.z + v.w * v.w;
  for (int off = 1; off < 64; off <<= 1) {
    s  += __shfl_xor(s, off, 64);
    s2 += __shfl_xor(s2, off, 64);
  }
  __shared__ float red[8];
  const int wave = tid >> 6, lane = tid & 63;
  if (lane == 0) { red[wave] = s; red[4 + wave] = s2; }
  __syncthreads();
  float S  = red[0] + red[1] + red[2] + red[3];
  float S2 = red[4] + red[5] + red[6] + red[7];
  float mean = S * (1.0f / DIM);
  float var  = S2 * (1.0f / DIM) - mean * mean;
  float rstd = rsqrtf(var + 1e-5f);
  float4 gv = *(const float4*)(g + tid * 4);
  float4 bv = *(const float4*)(b + tid * 4);
  float ox = (v.x - mean) * rstd * gv.x + bv.x;
  float oy = (v.y - mean) * rstd * gv.y + bv.y;
  float oz = (v.z - mean) * rstd * gv.z + bv.z;
  float ow = (v.w - mean) * rstd * gv.w + bv.w;
  int2 pk; pk.x = pack2(ox, oy); pk.y = pack2(oz, ow);
  *(int2*)(out + (size_t)t * DIM + tid * 4) = pk;
}

// ---------------------------------------------------------------------------
// Router: per-token LN + 4-way gate logits + softmax + top-2.
// NO global atomics (previous version serialized 24K same-line atomics,
// 318 us). Writes per-token probs (float4) + packed top-2 indices; the
// pi/fi reduction moves to moe_stats_kernel.
// ---------------------------------------------------------------------------
__global__ __launch_bounds__(128) void router_kernel(
    const float* __restrict__ xin, const float* __restrict__ g,
    const float* __restrict__ bb, const float* __restrict__ Wgp,
    float* __restrict__ stab, float* __restrict__ probs4, int* __restrict__ tops)
{
  const int t = blockIdx.x, tid = threadIdx.x;
  const float* row = xin + (size_t)t * DIM;
  float v[8]; float s = 0.f, s2 = 0.f;
#pragma unroll
  for (int k = 0; k < 8; ++k) {
    float u = row[tid + 128 * k];
    v[k] = u; s += u; s2 += u * u;
  }
  for (int off = 1; off < 64; off <<= 1) {
    s  += __shfl_xor(s, off, 64);
    s2 += __shfl_xor(s2, off, 64);
  }
  __shared__ float red[4];
  const int wv = tid >> 6, ln = tid & 63;
  if (ln == 0) { red[wv] = s; red[2 + wv] = s2; }
  __syncthreads();
  float S = red[0] + red[1], S2 = red[2] + red[3];
  float mean = S * (1.0f / DIM);
  float var  = S2 * (1.0f / DIM) - mean * mean;
  float rstd = rsqrtf(var + 1e-5f);
  float p0 = 0, p1 = 0, p2 = 0, p3 = 0;
#pragma unroll
  for (int k = 0; k < 8; ++k) {
    int i = tid + 128 * k;
    float hv = (v[k] - mean) * rstd * g[i] + bb[i];
    p0 += hv * Wgp[i];
    p1 += hv * Wgp[DIM + i];
    p2 += hv * Wgp[2 * DIM + i];
    p3 += hv * Wgp[3 * DIM + i];
  }
  __shared__ float sm[4][128];
  sm[0][tid] = p0; sm[1][tid] = p1; sm[2][tid] = p2; sm[3][tid] = p3;
  __syncthreads();
  for (int sft = 64; sft > 0; sft >>= 1) {
    if (tid < sft)
      for (int e = 0; e < 4; ++e) sm[e][tid] += sm[e][tid + sft];
    __syncthreads();
  }
  if (tid == 0) {
    float l[4] = { sm[0][0], sm[1][0], sm[2][0], sm[3][0] };
    float m = fmaxf(fmaxf(l[0], l[1]), fmaxf(l[2], l[3]));
    float pr[4]; float sum = 0.f;
    for (int e = 0; e < 4; ++e) { pr[e] = __expf(l[e] - m); sum += pr[e]; }
    for (int e = 0; e < 4; ++e) pr[e] /= sum;
    int i0 = 0;
    for (int e = 1; e < 4; ++e) if (pr[e] > pr[i0]) i0 = e;
    int i1 = -1;
    for (int e = 0; e < 4; ++e) if (e != i0 && (i1 < 0 || pr[e] > pr[i1])) i1 = e;
    float wsum = pr[i0] + pr[i1];
    for (int e = 0; e < 4; ++e)
      stab[(size_t)e * T_TOK + t] = (e == i0) ? pr[i0] / wsum : (e == i1) ? pr[i1] / wsum : 0.f;
    ((float4*)probs4)[t] = make_float4(pr[0], pr[1], pr[2], pr[3]);
    tops[t] = i0 | (i1 << 2);
  }
}

// Single-block reduction over per-token router outputs -> aux scalar.
// Replaces zero8 + 24K contended atomics + aux_kernel.
__global__ __launch_bounds__(256) void moe_stats_kernel(
    const float* __restrict__ probs4, const int* __restrict__ tops,
    float* __restrict__ outaux)
{
  const int tid = threadIdx.x;
  float pi0 = 0, pi1 = 0, pi2 = 0, pi3 = 0;
  float fi0 = 0, fi1 = 0, fi2 = 0, fi3 = 0;
  for (int t = tid; t < T_TOK; t += 256) {
    float4 p = ((const float4*)probs4)[t];
    pi0 += p.x; pi1 += p.y; pi2 += p.z; pi3 += p.w;
    int ii = tops[t];
    int a = ii & 3, b = (ii >> 2) & 3;
    fi0 += (a == 0 ? 1.f : 0.f) + (b == 0 ? 1.f : 0.f);
    fi1 += (a == 1 ? 1.f : 0.f) + (b == 1 ? 1.f : 0.f);
    fi2 += (a == 2 ? 1.f : 0.f) + (b == 2 ? 1.f : 0.f);
    fi3 += (a == 3 ? 1.f : 0.f) + (b == 3 ? 1.f : 0.f);
  }
  for (int off = 1; off < 64; off <<= 1) {
    pi0 += __shfl_xor(pi0, off, 64); pi1 += __shfl_xor(pi1, off, 64);
    pi2 += __shfl_xor(pi2, off, 64); pi3 += __shfl_xor(pi3, off, 64);
    fi0 += __shfl_xor(fi0, off, 64); fi1 += __shfl_xor(fi1, off, 64);
    fi2 += __shfl_xor(fi2, off, 64); fi3 += __shfl_xor(fi3, off, 64);
  }
  __shared__ float red[8][4];
  const int wv = tid >> 6, ln = tid & 63;
  if (ln == 0) {
    red[0][wv] = pi0; red[1][wv] = pi1; red[2][wv] = pi2; red[3][wv] = pi3;
    red[4][wv] = fi0; red[5][wv] = fi1; red[6][wv] = fi2; red[7][wv] = fi3;
  }
  __syncthreads();
  if (tid == 0) {
    float P[4], F[4];
    for (int e = 0; e < 4; ++e) {
      P[e] = red[e][0] + red[e][1] + red[e][2] + red[e][3];
      F[e] = red[4 + e][0] + red[4 + e][1] + red[4 + e][2] + red[4 + e][3];
    }
    float sacc = F[0] * P[0] + F[1] * P[1] + F[2] * P[2] + F[3] * P[3];
    outaux[0] = 0.01f * 4.0f * sacc / (2.0f * (float)T_TOK * (float)T_TOK);
  }
}

// y = bs_dn + sum_e stab[e]*be_dn[e]; y2 = 0
__global__ __launch_bounds__(256) void init_y_kernel(
    const float* __restrict__ bs_dn, const float* __restrict__ be_dn,
    const float* __restrict__ stab, float* __restrict__ y, float* __restrict__ y2)
{
  const int t = blockIdx.x, c = threadIdx.x;
  float s0 = stab[t], s1 = stab[T_TOK + t], s2 = stab[2 * T_TOK + t], s3 = stab[3 * T_TOK + t];
  float4 acc = ((const float4*)bs_dn)[c];
  float4 b0 = ((const float4*)(be_dn + 0 * DIM))[c];
  float4 b1 = ((const float4*)(be_dn + 1 * DIM))[c];
  float4 b2 = ((const float4*)(be_dn + 2 * DIM))[c];
  float4 b3 = ((const float4*)(be_dn + 3 * DIM))[c];
  acc.x += s0 * b0.x + s1 * b1.x + s2 * b2.x + s3 * b3.x;
  acc.y += s0 * b0.y + s1 * b1.y + s2 * b2.y + s3 * b3.y;
  acc.z += s0 * b0.z + s1 * b1.z + s2 * b2.z + s3 * b3.z;
  acc.w += s0 * b0.w + s1 * b1.w + s2 * b2.w + s3 * b3.w;
  ((float4*)(y + (size_t)t * DIM))[c] = acc;
  ((float4*)(y2 + (size_t)t * DIM))[c] = make_float4(0.f, 0.f, 0.f, 0.f);
}

__global__ __launch_bounds__(256) void add3_kernel(
    const float* __restrict__ a, const float* __restrict__ b,
    const float* __restrict__ c, float* __restrict__ out, int n)
{
  int i = blockIdx.x * 256 + threadIdx.x;
  if (i < n) out[i] = a[i] + b[i] + c[i];
}

// ---------------------------------------------------------------------------
extern "C" void kernel_launch(void* const* d_in, const int* in_sizes, int n_in,
                              void* d_out, int out_size, void* d_ws, size_t ws_size,
                              hipStream_t stream)
{
  const float* x      = (const float*)d_in[0];
  const float* ln1_g  = (const float*)d_in[1];
  const float* ln1_b  = (const float*)d_in[2];
  const float* Wqkv   = (const float*)d_in[3];
  const float* bqkv   = (const float*)d_in[4];
  const float* Wo     = (const float*)d_in[5];
  const float* bo     = (const float*)d_in[6];
  const float* ln2_g  = (const float*)d_in[7];
  const float* ln2_b  = (const float*)d_in[8];
  const float* Wg     = (const float*)d_in[9];
  const float* We_up  = (const float*)d_in[10];
  const float* be_up  = (const float*)d_in[11];
  const float* We_dn  = (const float*)d_in[12];
  const float* be_dn  = (const float*)d_in[13];
  const float* Ws_up  = (const float*)d_in[14];
  const float* bs_up  = (const float*)d_in[15];
  const float* Ws_dn  = (const float*)d_in[16];
  const float* bs_dn  = (const float*)d_in[17];

  float* out = (float*)d_out;
  const size_t TD = (size_t)T_TOK * DIM;   // 4,194,304

  // Workspace: ~104 MB
  char* w = (char*)d_ws;
  float* x1 = (float*)w;  w += TD * 4;                          // 16 MB
  float* y  = (float*)w;                                        // 16 MB
  unsigned short* o_bf = (unsigned short*)y;                    //   (o dead before init_y)
  w += TD * 4;
  float* y2 = (float*)w;  w += TD * 4;                          // 16 MB
  unsigned short* pool = (unsigned short*)w;                    // 32 MB: qkv_bf then up_bf
  unsigned short* qkv_bf = pool;
  unsigned short* up_bf  = pool;
  w += (size_t)T_TOK * HIDD * 2;
  unsigned short* h_bf = (unsigned short*)w;  w += TD * 2;      // 8 MB
  unsigned short* P1   = (unsigned short*)w;  w += (size_t)HIDD * DIM * 2;  // 8 MB
  unsigned short* P2   = (unsigned short*)w;  w += (size_t)HIDD * DIM * 2;  // 8 MB
  float* stab = (float*)w;  w += (size_t)NEXP * T_TOK * 4;      // 64 KB
  float* probs4 = (float*)w; w += (size_t)T_TOK * 4 * 4;        // 64 KB
  int*   tops   = (int*)w;   w += (size_t)T_TOK * 4;            // 16 KB

  auto cvt = [&](const float* src, unsigned short* dst, int n) {
    cvt_kernel<<<(n / 8 + 255) / 256, 256, 0, stream>>>(src, dst, n / 8);
  };

  // 1) h = LN1(x) -> bf16 ; Wqkv -> P1
  cvt(Wqkv, P1, 3 * DIM * DIM);
  ln_kernel<<<T_TOK, 256, 0, stream>>>(x, ln1_g, ln1_b, h_bf);
  // 2) qkv (bf16 only)
  gemm_bf16<<<dim3(3072 / 128, T_TOK / 128), 256, 0, stream>>>(
      h_bf, P1, bqkv, nullptr, nullptr, nullptr, nullptr, qkv_bf, T_TOK, 3072, DIM, 0);
  // 3) o = causal MFMA attention -> bf16
  attn_mfma<<<dim3(16, 2 * NHEAD), 256, 0, stream>>>(qkv_bf, o_bf);
  // 4) x1 = x + o @ Wo^T + bo
  cvt(Wo, P2, DIM * DIM);
  gemm_bf16<<<dim3(DIM / 128, T_TOK / 128), 256, 0, stream>>>(
      o_bf, P2, bo, x, nullptr, x1, nullptr, nullptr, T_TOK, DIM, DIM, GF_RESID);
  // 5) h2 = LN2(x1) -> bf16
  ln_kernel<<<T_TOK, 256, 0, stream>>>(x1, ln2_g, ln2_b, h_bf);
  // 6) router (fp32 inline LN from x1), atomic-free; then single-block stats
  router_kernel<<<T_TOK, 128, 0, stream>>>(x1, ln2_g, ln2_b, Wg, stab, probs4, tops);
  moe_stats_kernel<<<1, 256, 0, stream>>>(probs4, tops, out);
  // 7) y/y2 init with all down-proj biases folded in
  init_y_kernel<<<T_TOK, 256, 0, stream>>>(bs_dn, be_dn, stab, y, y2);
  // 8) shared MLP: up (gelu) then split-K down accumulate
  cvt(Ws_up, P1, HIDD * DIM);
  gemm_bf16<<<dim3(HIDD / 128, T_TOK / 128), 256, 0, stream>>>(
      h_bf, P1, bs_up, nullptr, nullptr, nullptr, nullptr, up_bf, T_TOK, HIDD, DIM, GF_GELU);
  cvt(Ws_dn, P2, DIM * HIDD);
  gemm_bf16<<<dim3(DIM / 128, T_TOK / 128, 2), 256, 0, stream>>>(
      up_bf, P2, nullptr, nullptr, nullptr, y, y2, nullptr, T_TOK, DIM, HIDD, GF_ACCUM);
  // 9) MoE experts: scale folded into up epilogue; down pure accumulate
  for (int e = 0; e < NEXP; ++e) {
    cvt(We_up + (size_t)e * HIDD * DIM, P1, HIDD * DIM);
    gemm_bf16<<<dim3(HIDD / 128, T_TOK / 128), 256, 0, stream>>>(
        h_bf, P1, be_up + (size_t)e * HIDD,
        nullptr, stab + (size_t)e * T_TOK, nullptr, nullptr, up_bf,
        T_TOK, HIDD, DIM, GF_GELU | GF_SCALE);
    cvt(We_dn + (size_t)e * DIM * HIDD, P2, DIM * HIDD);
    gemm_bf16<<<dim3(DIM / 128, T_TOK / 128, 2), 256, 0, stream>>>(
        up_bf, P2, nullptr, nullptr, nullptr, y, y2, nullptr,
        T_TOK, DIM, HIDD, GF_ACCUM);
  }
  // 10) out = x1 + y + y2
  add3_kernel<<<(int)(TD / 256), 256, 0, stream>>>(x1, y, y2, out + 1, (int)TD);
}

// Round 2
// 1350.651 us; speedup vs baseline: 1.2495x; 1.0191x over previous
//
#include <hip/hip_runtime.h>
#include <hip/hip_bf16.h>

// Problem constants: B=2, S=2048, D=1024, H=16, HD=64, E=4, K=2, HID=4096, T=4096
#define T_TOK 4096
#define DIM   1024
#define NHEAD 16
#define HDIM  64
#define SEQ   2048
#define NEXP  4
#define HIDD  4096
#define QS    66   // attention LDS row stride (shorts)

typedef short bf16x8 __attribute__((ext_vector_type(8)));
typedef float f32x4  __attribute__((ext_vector_type(4)));

enum { GF_GELU = 1, GF_RESID = 2, GF_SCALE = 4, GF_ACCUM = 8 };

__device__ inline unsigned short f2bf(float f) {
  union { float f; unsigned u; } v; v.f = f;
  unsigned r = v.u + 0x7FFFu + ((v.u >> 16) & 1u);
  return (unsigned short)(r >> 16);
}
__device__ inline int pack2(float a, float b) {
  return (int)((unsigned)f2bf(a) | ((unsigned)f2bf(b) << 16));
}
// Fast tanh-approx GELU: gelu(x) = 0.5x(1+tanh(z)), z = c(x+0.044715x^3)
//                              = x - x / (1 + e^{2z})
// Single v_exp_f32 + v_rcp_f32 (~8 VALU) vs libm tanhf (~100 VALU w/ branches).
// Saturates correctly: x->+inf => e^{2z}=inf, rcp=0, gelu=x; x->-inf => gelu=0.
__device__ inline float gelu_f(float x) {
  float u = 1.5957691216057308f * x * (1.0f + 0.044715f * x * x);  // 2z
  float w = __expf(u);
  return x - x * __builtin_amdgcn_rcpf(w + 1.0f);
}
__device__ inline void gld_lds16(const unsigned short* g, unsigned short* l) {
  __builtin_amdgcn_global_load_lds(
      (const __attribute__((address_space(1))) void*)g,
      (__attribute__((address_space(3))) void*)l, 16, 0, 0);
}

// ---------------------------------------------------------------------------
__global__ __launch_bounds__(256) void cvt_kernel(
    const float* __restrict__ in, unsigned short* __restrict__ out, int n8)
{
  int i = blockIdx.x * 256 + threadIdx.x;
  if (i >= n8) return;
  const float4* p = (const float4*)in + (size_t)i * 2;
  float4 v0 = p[0], v1 = p[1];
  int4 pk = make_int4(pack2(v0.x, v0.y), pack2(v0.z, v0.w),
                      pack2(v1.x, v1.y), pack2(v1.z, v1.w));
  *(int4*)(out + (size_t)i * 8) = pk;
}

// ---------------------------------------------------------------------------
// m97-style bf16 GEMM: C = A @ W^T (+epilogue). 128x128 tile, BK=32, 256 thr.
// Optional split-K via gridDim.z (z=0 -> C, z=1 -> Cz; both pre-initialized).
// ---------------------------------------------------------------------------
__global__ __launch_bounds__(256) void gemm_bf16(
    const unsigned short* __restrict__ A, const unsigned short* __restrict__ W,
    const float* __restrict__ bias, const float* __restrict__ resid,
    const float* __restrict__ scale, float* __restrict__ C,
    float* __restrict__ Cz, unsigned short* __restrict__ C2,
    int M, int N, int Kd, int flags)
{
  __shared__ __align__(16) unsigned short As[128 * 32];
  __shared__ __align__(16) unsigned short Bs[128 * 32];

  const int tid  = threadIdx.x;
  const int wave = tid >> 6, lane = tid & 63;
  const int bm = blockIdx.y, bn = blockIdx.x;
  const int kz = blockIdx.z;
  const int kseg = Kd / gridDim.z;       // K-range for this z-slice
  if (kz == 1) C = Cz;

  const int srow = lane >> 2;            // 0..15
  const int scol = (lane & 3) << 3;      // 0,8,16,24 (bf16 elems)
  const unsigned short* Ag = A + (size_t)(bm * 128 + wave * 32 + srow) * Kd + scol + (size_t)kz * kseg;
  const unsigned short* Wg = W + (size_t)(bn * 128 + wave * 32 + srow) * Kd + scol + (size_t)kz * kseg;
  unsigned short* AsBase = As + wave * 32 * 32;
  unsigned short* BsBase = Bs + wave * 32 * 32;

  const int wm = wave >> 1, wn = wave & 1;
  const int fr = lane & 15;
  const int fq = lane >> 4;

  f32x4 acc[4][4] = {};

  for (int k0 = 0; k0 < kseg; k0 += 32) {
    __syncthreads();
    gld_lds16(Ag + k0,            AsBase);
    gld_lds16(Ag + k0 + 16 * Kd,  AsBase + 16 * 32);
    gld_lds16(Wg + k0,            BsBase);
    gld_lds16(Wg + k0 + 16 * Kd,  BsBase + 16 * 32);
    __syncthreads();
    bf16x8 a[4], b[4];
#pragma unroll
    for (int i = 0; i < 4; ++i) {
      a[i] = *(const bf16x8*)&As[(wm * 64 + i * 16 + fr) * 32 + fq * 8];
      b[i] = *(const bf16x8*)&Bs[(wn * 64 + i * 16 + fr) * 32 + fq * 8];
    }
#pragma unroll
    for (int mt = 0; mt < 4; ++mt)
#pragma unroll
      for (int nt = 0; nt < 4; ++nt)
        acc[mt][nt] = __builtin_amdgcn_mfma_f32_16x16x32_bf16(a[mt], b[nt], acc[mt][nt], 0, 0, 0);
  }

#pragma unroll
  for (int mt = 0; mt < 4; ++mt)
#pragma unroll
    for (int nt = 0; nt < 4; ++nt)
#pragma unroll
      for (int r = 0; r < 4; ++r) {
        int row = bm * 128 + wm * 64 + mt * 16 + fq * 4 + r;
        int col = bn * 128 + wn * 64 + nt * 16 + fr;
        float v = acc[mt][nt][r];
        if (bias) v += bias[col];
        if (flags & GF_GELU) v = gelu_f(v);
        if (flags & GF_RESID) v += resid[(size_t)row * N + col];
        if (flags & GF_SCALE) v *= scale[row];
        size_t idx = (size_t)row * N + col;
        if (C) { if (flags & GF_ACCUM) C[idx] += v; else C[idx] = v; }
        if (C2) C2[idx] = f2bf(v);
      }
}

// ---------------------------------------------------------------------------
// bf16 MFMA flash attention, causal, paired Q-tiles. Grid (16, B*H), 256 thr.
// Per wave: 16 Q-rows. S via 8 QK^T MFMAs; online softmax in registers
// (quad-shuffles); P roundtrip via wave-private LDS; PV via 8 MFMAs with V^T.
// ---------------------------------------------------------------------------
__global__ __launch_bounds__(256) void attn_mfma(
    const unsigned short* __restrict__ qkv, unsigned short* __restrict__ o)
{
  __shared__ __align__(16) unsigned short Qs[64 * QS];
  __shared__ __align__(16) unsigned short Ks[64 * QS];
  __shared__ __align__(16) unsigned short Vt[64 * QS];  // transposed: Vt[d][k]
  __shared__ __align__(16) unsigned short Ps[64 * QS];  // wave-private 16-row bands

  const int tid  = threadIdx.x;
  const int wave = tid >> 6, lane = tid & 63;
  const int quad = lane >> 4, l15 = lane & 15;
  const int bh = blockIdx.y, b = bh >> 4, h = bh & 15;

  const int srow = tid >> 2;            // staging row 0..63
  const int scol = (tid & 3) << 4;      // staging col base (16 shorts)

  for (int half = 0; half < 2; ++half) {
    const int qb = half ? (31 - (int)blockIdx.x) : (int)blockIdx.x;
    const int q0 = qb << 6;

    __syncthreads();  // prior half fully done before overwriting Qs
    {
      const unsigned short* qp = qkv + ((size_t)(b * SEQ + q0 + srow)) * 3072 + h * 64 + scol;
      *(int4*)&Qs[srow * QS + scol]     = *(const int4*)qp;
      *(int4*)&Qs[srow * QS + scol + 8] = *(const int4*)(qp + 8);
    }
    __syncthreads();
    bf16x8 qf0 = *(const bf16x8*)&Qs[(wave * 16 + l15) * QS + quad * 8];
    bf16x8 qf1 = *(const bf16x8*)&Qs[(wave * 16 + l15) * QS + 32 + quad * 8];

    f32x4 Oc[4] = {};
    float mr[4] = {-1e30f, -1e30f, -1e30f, -1e30f};
    float ls[4] = {0.f, 0.f, 0.f, 0.f};

    for (int kt = 0; kt <= qb; ++kt) {
      __syncthreads();  // previous iteration's K/Vt reads complete
      {
        const unsigned short* kp = qkv + ((size_t)(b * SEQ + (kt << 6) + srow)) * 3072 + 1024 + h * 64 + scol;
        const unsigned short* vp = kp + 1024;
        *(int4*)&Ks[srow * QS + scol]     = *(const int4*)kp;
        *(int4*)&Ks[srow * QS + scol + 8] = *(const int4*)(kp + 8);
        unsigned short vs[16];
        *(int4*)&vs[0] = *(const int4*)vp;
        *(int4*)&vs[8] = *(const int4*)(vp + 8);
#pragma unroll
        for (int i = 0; i < 16; ++i)
          Vt[(scol + i) * QS + srow] = vs[i];
      }
      __syncthreads();

      // S = Q K^T  (per wave: 16 rows x 64 cols = 4 col-tiles)
      f32x4 sc[4] = {};
#pragma unroll
      for (int ct = 0; ct < 4; ++ct) {
        bf16x8 k0 = *(const bf16x8*)&Ks[(ct * 16 + l15) * QS + quad * 8];
        bf16x8 k1 = *(const bf16x8*)&Ks[(ct * 16 + l15) * QS + 32 + quad * 8];
        sc[ct] = __builtin_amdgcn_mfma_f32_16x16x32_bf16(qf0, k0, sc[ct], 0, 0, 0);
        sc[ct] = __builtin_amdgcn_mfma_f32_16x16x32_bf16(qf1, k1, sc[ct], 0, 0, 0);
      }

      // scale + causal mask (C-layout: local col = ct*16+l15,
      // local row within tile = wave*16 + quad*4 + r  — wave offset REQUIRED)
      float sv[4][4];
      const bool diag = (kt == qb);
#pragma unroll
      for (int ct = 0; ct < 4; ++ct)
#pragma unroll
        for (int r = 0; r < 4; ++r) {
          float v = sc[ct][r] * 0.125f;
          if (diag && (ct * 16 + l15) > (wave * 16 + quad * 4 + r)) v = -1e9f;
          sv[ct][r] = v;
        }
      // row stats (rows live in one 16-lane group)
      float rm[4], rs[4];
#pragma unroll
      for (int r = 0; r < 4; ++r)
        rm[r] = fmaxf(fmaxf(sv[0][r], sv[1][r]), fmaxf(sv[2][r], sv[3][r]));
#pragma unroll
      for (int m = 1; m < 16; m <<= 1)
#pragma unroll
        for (int r = 0; r < 4; ++r) rm[r] = fmaxf(rm[r], __shfl_xor(rm[r], m, 16));
      float al[4];
#pragma unroll
      for (int r = 0; r < 4; ++r) {
        float nm = fmaxf(mr[r], rm[r]);
        al[r] = __expf(mr[r] - nm);
        mr[r] = nm;
        rs[r] = 0.f;
      }
#pragma unroll
      for (int ct = 0; ct < 4; ++ct)
#pragma unroll
        for (int r = 0; r < 4; ++r) {
          float p = __expf(sv[ct][r] - mr[r]);
          sv[ct][r] = p;
          rs[r] += p;
        }
#pragma unroll
      for (int m = 1; m < 16; m <<= 1)
#pragma unroll
        for (int r = 0; r < 4; ++r) rs[r] += __shfl_xor(rs[r], m, 16);
#pragma unroll
      for (int r = 0; r < 4; ++r) {
        ls[r] = ls[r] * al[r] + rs[r];
        for (int ct = 0; ct < 4; ++ct) Oc[ct][r] *= al[r];
      }
      // P -> LDS (wave-private band, no barrier needed)
#pragma unroll
      for (int ct = 0; ct < 4; ++ct)
#pragma unroll
        for (int r = 0; r < 4; ++r)
          Ps[(wave * 16 + quad * 4 + r) * QS + ct * 16 + l15] = f2bf(sv[ct][r]);
      // PV
      bf16x8 pf0 = *(const bf16x8*)&Ps[(wave * 16 + l15) * QS + quad * 8];
      bf16x8 pf1 = *(const bf16x8*)&Ps[(wave * 16 + l15) * QS + 32 + quad * 8];
#pragma unroll
      for (int ct = 0; ct < 4; ++ct) {
        bf16x8 v0 = *(const bf16x8*)&Vt[(ct * 16 + l15) * QS + quad * 8];
        bf16x8 v1 = *(const bf16x8*)&Vt[(ct * 16 + l15) * QS + 32 + quad * 8];
        Oc[ct] = __builtin_amdgcn_mfma_f32_16x16x32_bf16(pf0, v0, Oc[ct], 0, 0, 0);
        Oc[ct] = __builtin_amdgcn_mfma_f32_16x16x32_bf16(pf1, v1, Oc[ct], 0, 0, 0);
      }
    }

#pragma unroll
    for (int r = 0; r < 4; ++r) {
      float inv = 1.0f / ls[r];
      unsigned short* orow = o + ((size_t)(b * SEQ + q0 + wave * 16 + quad * 4 + r)) * DIM + h * 64;
#pragma unroll
      for (int ct = 0; ct < 4; ++ct)
        orow[ct * 16 + l15] = f2bf(Oc[ct][r] * inv);
    }
  }
}

// ---------------------------------------------------------------------------
__global__ __launch_bounds__(256) void ln_kernel(
    const float* __restrict__ x, const float* __restrict__ g,
    const float* __restrict__ b, unsigned short* __restrict__ out)
{
  const int t = blockIdx.x, tid = threadIdx.x;
  const float* row = x + (size_t)t * DIM;
  float4 v = *(const float4*)(row + tid * 4);
  float s  = v.x + v.y + v.z + v.w;
  float s2 = v.x * v.x + v.y * v.y + v.z * v.z + v.w * v.w;
  for (int off = 1; off < 64; off <<= 1) {
    s  += __shfl_xor(s, off, 64);
    s2 += __shfl_xor(s2, off, 64);
  }
  __shared__ float red[8];
  const int wave = tid >> 6, lane = tid & 63;
  if (lane == 0) { red[wave] = s; red[4 + wave] = s2; }
  __syncthreads();
  float S  = red[0] + red[1] + red[2] + red[3];
  float S2 = red[4] + red[5] + red[6] + red[7];
  float mean = S * (1.0f / DIM);
  float var  = S2 * (1.0f / DIM) - mean * mean;
  float rstd = rsqrtf(var + 1e-5f);
  float4 gv = *(const float4*)(g + tid * 4);
  float4 bv = *(const float4*)(b + tid * 4);
  float ox = (v.x - mean) * rstd * gv.x + bv.x;
  float oy = (v.y - mean) * rstd * gv.y + bv.y;
  float oz = (v.z - mean) * rstd * gv.z + bv.z;
  float ow = (v.w - mean) * rstd * gv.w + bv.w;
  int2 pk; pk.x = pack2(ox, oy); pk.y = pack2(oz, ow);
  *(int2*)(out + (size_t)t * DIM + tid * 4) = pk;
}

// ---------------------------------------------------------------------------
// Router: per-token LN + 4-way gate logits + softmax + top-2.
// Atomic-free: writes per-token probs (float4) + packed top-2 indices; the
// pi/fi reduction happens in moe_stats_kernel.
// ---------------------------------------------------------------------------
__global__ __launch_bounds__(128) void router_kernel(
    const float* __restrict__ xin, const float* __restrict__ g,
    const float* __restrict__ bb, const float* __restrict__ Wgp,
    float* __restrict__ stab, float* __restrict__ probs4, int* __restrict__ tops)
{
  const int t = blockIdx.x, tid = threadIdx.x;
  const float* row = xin + (size_t)t * DIM;
  float v[8]; float s = 0.f, s2 = 0.f;
#pragma unroll
  for (int k = 0; k < 8; ++k) {
    float u = row[tid + 128 * k];
    v[k] = u; s += u; s2 += u * u;
  }
  for (int off = 1; off < 64; off <<= 1) {
    s  += __shfl_xor(s, off, 64);
    s2 += __shfl_xor(s2, off, 64);
  }
  __shared__ float red[4];
  const int wv = tid >> 6, ln = tid & 63;
  if (ln == 0) { red[wv] = s; red[2 + wv] = s2; }
  __syncthreads();
  float S = red[0] + red[1], S2 = red[2] + red[3];
  float mean = S * (1.0f / DIM);
  float var  = S2 * (1.0f / DIM) - mean * mean;
  float rstd = rsqrtf(var + 1e-5f);
  float p0 = 0, p1 = 0, p2 = 0, p3 = 0;
#pragma unroll
  for (int k = 0; k < 8; ++k) {
    int i = tid + 128 * k;
    float hv = (v[k] - mean) * rstd * g[i] + bb[i];
    p0 += hv * Wgp[i];
    p1 += hv * Wgp[DIM + i];
    p2 += hv * Wgp[2 * DIM + i];
    p3 += hv * Wgp[3 * DIM + i];
  }
  __shared__ float sm[4][128];
  sm[0][tid] = p0; sm[1][tid] = p1; sm[2][tid] = p2; sm[3][tid] = p3;
  __syncthreads();
  for (int sft = 64; sft > 0; sft >>= 1) {
    if (tid < sft)
      for (int e = 0; e < 4; ++e) sm[e][tid] += sm[e][tid + sft];
    __syncthreads();
  }
  if (tid == 0) {
    float l[4] = { sm[0][0], sm[1][0], sm[2][0], sm[3][0] };
    float m = fmaxf(fmaxf(l[0], l[1]), fmaxf(l[2], l[3]));
    float pr[4]; float sum = 0.f;
    for (int e = 0; e < 4; ++e) { pr[e] = __expf(l[e] - m); sum += pr[e]; }
    for (int e = 0; e < 4; ++e) pr[e] /= sum;
    int i0 = 0;
    for (int e = 1; e < 4; ++e) if (pr[e] > pr[i0]) i0 = e;
    int i1 = -1;
    for (int e = 0; e < 4; ++e) if (e != i0 && (i1 < 0 || pr[e] > pr[i1])) i1 = e;
    float wsum = pr[i0] + pr[i1];
    for (int e = 0; e < 4; ++e)
      stab[(size_t)e * T_TOK + t] = (e == i0) ? pr[i0] / wsum : (e == i1) ? pr[i1] / wsum : 0.f;
    ((float4*)probs4)[t] = make_float4(pr[0], pr[1], pr[2], pr[3]);
    tops[t] = i0 | (i1 << 2);
  }
}

// Single-block reduction over per-token router outputs -> aux scalar.
__global__ __launch_bounds__(256) void moe_stats_kernel(
    const float* __restrict__ probs4, const int* __restrict__ tops,
    float* __restrict__ outaux)
{
  const int tid = threadIdx.x;
  float pi0 = 0, pi1 = 0, pi2 = 0, pi3 = 0;
  float fi0 = 0, fi1 = 0, fi2 = 0, fi3 = 0;
  for (int t = tid; t < T_TOK; t += 256) {
    float4 p = ((const float4*)probs4)[t];
    pi0 += p.x; pi1 += p.y; pi2 += p.z; pi3 += p.w;
    int ii = tops[t];
    int a = ii & 3, b = (ii >> 2) & 3;
    fi0 += (a == 0 ? 1.f : 0.f) + (b == 0 ? 1.f : 0.f);
    fi1 += (a == 1 ? 1.f : 0.f) + (b == 1 ? 1.f : 0.f);
    fi2 += (a == 2 ? 1.f : 0.f) + (b == 2 ? 1.f : 0.f);
    fi3 += (a == 3 ? 1.f : 0.f) + (b == 3 ? 1.f : 0.f);
  }
  for (int off = 1; off < 64; off <<= 1) {
    pi0 += __shfl_xor(pi0, off, 64); pi1 += __shfl_xor(pi1, off, 64);
    pi2 += __shfl_xor(pi2, off, 64); pi3 += __shfl_xor(pi3, off, 64);
    fi0 += __shfl_xor(fi0, off, 64); fi1 += __shfl_xor(fi1, off, 64);
    fi2 += __shfl_xor(fi2, off, 64); fi3 += __shfl_xor(fi3, off, 64);
  }
  __shared__ float red[8][4];
  const int wv = tid >> 6, ln = tid & 63;
  if (ln == 0) {
    red[0][wv] = pi0; red[1][wv] = pi1; red[2][wv] = pi2; red[3][wv] = pi3;
    red[4][wv] = fi0; red[5][wv] = fi1; red[6][wv] = fi2; red[7][wv] = fi3;
  }
  __syncthreads();
  if (tid == 0) {
    float P[4], F[4];
    for (int e = 0; e < 4; ++e) {
      P[e] = red[e][0] + red[e][1] + red[e][2] + red[e][3];
      F[e] = red[4 + e][0] + red[4 + e][1] + red[4 + e][2] + red[4 + e][3];
    }
    float sacc = F[0] * P[0] + F[1] * P[1] + F[2] * P[2] + F[3] * P[3];
    outaux[0] = 0.01f * 4.0f * sacc / (2.0f * (float)T_TOK * (float)T_TOK);
  }
}

// y = bs_dn + sum_e stab[e]*be_dn[e]; y2 = 0
__global__ __launch_bounds__(256) void init_y_kernel(
    const float* __restrict__ bs_dn, const float* __restrict__ be_dn,
    const float* __restrict__ stab, float* __restrict__ y, float* __restrict__ y2)
{
  const int t = blockIdx.x, c = threadIdx.x;
  float s0 = stab[t], s1 = stab[T_TOK + t], s2 = stab[2 * T_TOK + t], s3 = stab[3 * T_TOK + t];
  float4 acc = ((const float4*)bs_dn)[c];
  float4 b0 = ((const float4*)(be_dn + 0 * DIM))[c];
  float4 b1 = ((const float4*)(be_dn + 1 * DIM))[c];
  float4 b2 = ((const float4*)(be_dn + 2 * DIM))[c];
  float4 b3 = ((const float4*)(be_dn + 3 * DIM))[c];
  acc.x += s0 * b0.x + s1 * b1.x + s2 * b2.x + s3 * b3.x;
  acc.y += s0 * b0.y + s1 * b1.y + s2 * b2.y + s3 * b3.y;
  acc.z += s0 * b0.z + s1 * b1.z + s2 * b2.z + s3 * b3.z;
  acc.w += s0 * b0.w + s1 * b1.w + s2 * b2.w + s3 * b3.w;
  ((float4*)(y + (size_t)t * DIM))[c] = acc;
  ((float4*)(y2 + (size_t)t * DIM))[c] = make_float4(0.f, 0.f, 0.f, 0.f);
}

__global__ __launch_bounds__(256) void add3_kernel(
    const float* __restrict__ a, const float* __restrict__ b,
    const float* __restrict__ c, float* __restrict__ out, int n)
{
  int i = blockIdx.x * 256 + threadIdx.x;
  if (i < n) out[i] = a[i] + b[i] + c[i];
}

// ---------------------------------------------------------------------------
extern "C" void kernel_launch(void* const* d_in, const int* in_sizes, int n_in,
                              void* d_out, int out_size, void* d_ws, size_t ws_size,
                              hipStream_t stream)
{
  const float* x      = (const float*)d_in[0];
  const float* ln1_g  = (const float*)d_in[1];
  const float* ln1_b  = (const float*)d_in[2];
  const float* Wqkv   = (const float*)d_in[3];
  const float* bqkv   = (const float*)d_in[4];
  const float* Wo     = (const float*)d_in[5];
  const float* bo     = (const float*)d_in[6];
  const float* ln2_g  = (const float*)d_in[7];
  const float* ln2_b  = (const float*)d_in[8];
  const float* Wg     = (const float*)d_in[9];
  const float* We_up  = (const float*)d_in[10];
  const float* be_up  = (const float*)d_in[11];
  const float* We_dn  = (const float*)d_in[12];
  const float* be_dn  = (const float*)d_in[13];
  const float* Ws_up  = (const float*)d_in[14];
  const float* bs_up  = (const float*)d_in[15];
  const float* Ws_dn  = (const float*)d_in[16];
  const float* bs_dn  = (const float*)d_in[17];

  float* out = (float*)d_out;
  const size_t TD = (size_t)T_TOK * DIM;   // 4,194,304

  // Workspace: ~104 MB
  char* w = (char*)d_ws;
  float* x1 = (float*)w;  w += TD * 4;                          // 16 MB
  float* y  = (float*)w;                                        // 16 MB
  unsigned short* o_bf = (unsigned short*)y;                    //   (o dead before init_y)
  w += TD * 4;
  float* y2 = (float*)w;  w += TD * 4;                          // 16 MB
  unsigned short* pool = (unsigned short*)w;                    // 32 MB: qkv_bf then up_bf
  unsigned short* qkv_bf = pool;
  unsigned short* up_bf  = pool;
  w += (size_t)T_TOK * HIDD * 2;
  unsigned short* h_bf = (unsigned short*)w;  w += TD * 2;      // 8 MB
  unsigned short* P1   = (unsigned short*)w;  w += (size_t)HIDD * DIM * 2;  // 8 MB
  unsigned short* P2   = (unsigned short*)w;  w += (size_t)HIDD * DIM * 2;  // 8 MB
  float* stab = (float*)w;  w += (size_t)NEXP * T_TOK * 4;      // 64 KB
  float* probs4 = (float*)w; w += (size_t)T_TOK * 4 * 4;        // 64 KB
  int*   tops   = (int*)w;   w += (size_t)T_TOK * 4;            // 16 KB

  auto cvt = [&](const float* src, unsigned short* dst, int n) {
    cvt_kernel<<<(n / 8 + 255) / 256, 256, 0, stream>>>(src, dst, n / 8);
  };

  // 1) h = LN1(x) -> bf16 ; Wqkv -> P1
  cvt(Wqkv, P1, 3 * DIM * DIM);
  ln_kernel<<<T_TOK, 256, 0, stream>>>(x, ln1_g, ln1_b, h_bf);
  // 2) qkv (bf16 only)
  gemm_bf16<<<dim3(3072 / 128, T_TOK / 128), 256, 0, stream>>>(
      h_bf, P1, bqkv, nullptr, nullptr, nullptr, nullptr, qkv_bf, T_TOK, 3072, DIM, 0);
  // 3) o = causal MFMA attention -> bf16
  attn_mfma<<<dim3(16, 2 * NHEAD), 256, 0, stream>>>(qkv_bf, o_bf);
  // 4) x1 = x + o @ Wo^T + bo
  cvt(Wo, P2, DIM * DIM);
  gemm_bf16<<<dim3(DIM / 128, T_TOK / 128), 256, 0, stream>>>(
      o_bf, P2, bo, x, nullptr, x1, nullptr, nullptr, T_TOK, DIM, DIM, GF_RESID);
  // 5) h2 = LN2(x1) -> bf16
  ln_kernel<<<T_TOK, 256, 0, stream>>>(x1, ln2_g, ln2_b, h_bf);
  // 6) router (fp32 inline LN from x1), atomic-free; then single-block stats
  router_kernel<<<T_TOK, 128, 0, stream>>>(x1, ln2_g, ln2_b, Wg, stab, probs4, tops);
  moe_stats_kernel<<<1, 256, 0, stream>>>(probs4, tops, out);
  // 7) y/y2 init with all down-proj biases folded in
  init_y_kernel<<<T_TOK, 256, 0, stream>>>(bs_dn, be_dn, stab, y, y2);
  // 8) shared MLP: up (gelu) then split-K down accumulate
  cvt(Ws_up, P1, HIDD * DIM);
  gemm_bf16<<<dim3(HIDD / 128, T_TOK / 128), 256, 0, stream>>>(
      h_bf, P1, bs_up, nullptr, nullptr, nullptr, nullptr, up_bf, T_TOK, HIDD, DIM, GF_GELU);
  cvt(Ws_dn, P2, DIM * HIDD);
  gemm_bf16<<<dim3(DIM / 128, T_TOK / 128, 2), 256, 0, stream>>>(
      up_bf, P2, nullptr, nullptr, nullptr, y, y2, nullptr, T_TOK, DIM, HIDD, GF_ACCUM);
  // 9) MoE experts: scale folded into up epilogue; down pure accumulate
  for (int e = 0; e < NEXP; ++e) {
    cvt(We_up + (size_t)e * HIDD * DIM, P1, HIDD * DIM);
    gemm_bf16<<<dim3(HIDD / 128, T_TOK / 128), 256, 0, stream>>>(
        h_bf, P1, be_up + (size_t)e * HIDD,
        nullptr, stab + (size_t)e * T_TOK, nullptr, nullptr, up_bf,
        T_TOK, HIDD, DIM, GF_GELU | GF_SCALE);
    cvt(We_dn + (size_t)e * DIM * HIDD, P2, DIM * HIDD);
    gemm_bf16<<<dim3(DIM / 128, T_TOK / 128, 2), 256, 0, stream>>>(
        up_bf, P2, nullptr, nullptr, nullptr, y, y2, nullptr,
        T_TOK, DIM, HIDD, GF_ACCUM);
  }
  // 10) out = x1 + y + y2
  add3_kernel<<<(int)(TD / 256), 256, 0, stream>>>(x1, y, y2, out + 1, (int)TD);
}

// Round 3
// 1231.916 us; speedup vs baseline: 1.3699x; 1.0964x over previous
//
#include <hip/hip_runtime.h>
#include <hip/hip_bf16.h>

// Problem constants: B=2, S=2048, D=1024, H=16, HD=64, E=4, K=2, HID=4096, T=4096
#define T_TOK 4096
#define DIM   1024
#define NHEAD 16
#define HDIM  64
#define SEQ   2048
#define NEXP  4
#define HIDD  4096
#define QS    66   // attention LDS row stride (shorts)

typedef short bf16x8 __attribute__((ext_vector_type(8)));
typedef float f32x4  __attribute__((ext_vector_type(4)));

enum { GF_GELU = 1, GF_RESID = 2, GF_SCALE = 4, GF_ACCUM = 8 };

__device__ inline unsigned short f2bf(float f) {
  union { float f; unsigned u; } v; v.f = f;
  unsigned r = v.u + 0x7FFFu + ((v.u >> 16) & 1u);
  return (unsigned short)(r >> 16);
}
__device__ inline int pack2(float a, float b) {
  return (int)((unsigned)f2bf(a) | ((unsigned)f2bf(b) << 16));
}
// Fast tanh-approx GELU: gelu(x) = 0.5x(1+tanh(z)) = x - x/(1+e^{2z})
__device__ inline float gelu_f(float x) {
  float u = 1.5957691216057308f * x * (1.0f + 0.044715f * x * x);  // 2z
  float w = __expf(u);
  return x - x * __builtin_amdgcn_rcpf(w + 1.0f);
}
__device__ inline void gld_lds16(const unsigned short* g, unsigned short* l) {
  __builtin_amdgcn_global_load_lds(
      (const __attribute__((address_space(1))) void*)g,
      (__attribute__((address_space(3))) void*)l, 16, 0, 0);
}

// ---------------------------------------------------------------------------
__global__ __launch_bounds__(256) void cvt_kernel(
    const float* __restrict__ in, unsigned short* __restrict__ out, int n8)
{
  int i = blockIdx.x * 256 + threadIdx.x;
  if (i >= n8) return;
  const float4* p = (const float4*)in + (size_t)i * 2;
  float4 v0 = p[0], v1 = p[1];
  int4 pk = make_int4(pack2(v0.x, v0.y), pack2(v0.z, v0.w),
                      pack2(v1.x, v1.y), pack2(v1.z, v1.w));
  *(int4*)(out + (size_t)i * 8) = pk;
}

// ---------------------------------------------------------------------------
// bf16 GEMM: C = A @ W^T (+epilogue). 128x128 tile, BK=64, 256 thr.
// LDS layout [128][64] with XOR chunk swizzle: phys chunk c' = c ^ (row&7)
// (chunks of 8 shorts = 16B). global_load_lds writes linearly, so the
// swizzle is applied by pre-swizzling each lane's GLOBAL source column
// (rule 21: linear dest + inverse-swizzled source + swizzled read).
// Reads: 16 lanes (fr=0..15) at fixed (ks,fq) hit 8 distinct 16B slots
// -> exactly 2 lanes/bank (free). BK=64 halves barrier count per MFMA.
// ---------------------------------------------------------------------------
__global__ __launch_bounds__(256) void gemm_bf16(
    const unsigned short* __restrict__ A, const unsigned short* __restrict__ W,
    const float* __restrict__ bias, const float* __restrict__ resid,
    const float* __restrict__ scale, float* __restrict__ C,
    float* __restrict__ Cz, unsigned short* __restrict__ C2,
    int M, int N, int Kd, int flags)
{
  __shared__ __align__(16) unsigned short As[128 * 64];
  __shared__ __align__(16) unsigned short Bs[128 * 64];

  const int tid  = threadIdx.x;
  const int wave = tid >> 6, lane = tid & 63;
  const int bm = blockIdx.y, bn = blockIdx.x;
  const int kz = blockIdx.z;
  const int kseg = Kd / gridDim.z;       // K-range for this z-slice
  if (kz == 1) C = Cz;

  // staging: wave stages rows [wave*32, wave*32+32). Per call: 8 rows x 128B.
  const int srow = lane >> 3;                       // 0..7
  const int scol = ((lane & 7) ^ srow) << 3;        // inverse-swizzled source chunk
  const unsigned short* Ag = A + (size_t)(bm * 128 + wave * 32 + srow) * Kd + scol + (size_t)kz * kseg;
  const unsigned short* Wg = W + (size_t)(bn * 128 + wave * 32 + srow) * Kd + scol + (size_t)kz * kseg;
  unsigned short* AsBase = As + wave * 32 * 64;
  unsigned short* BsBase = Bs + wave * 32 * 64;

  const int wm = wave >> 1, wn = wave & 1;
  const int fr = lane & 15;
  const int fq = lane >> 4;
  const int f7 = fr & 7;

  f32x4 acc[4][4] = {};

  for (int k0 = 0; k0 < kseg; k0 += 64) {
    __syncthreads();
    gld_lds16(Ag + k0,            AsBase);
    gld_lds16(Ag + k0 +  8 * Kd,  AsBase +  8 * 64);
    gld_lds16(Ag + k0 + 16 * Kd,  AsBase + 16 * 64);
    gld_lds16(Ag + k0 + 24 * Kd,  AsBase + 24 * 64);
    gld_lds16(Wg + k0,            BsBase);
    gld_lds16(Wg + k0 +  8 * Kd,  BsBase +  8 * 64);
    gld_lds16(Wg + k0 + 16 * Kd,  BsBase + 16 * 64);
    gld_lds16(Wg + k0 + 24 * Kd,  BsBase + 24 * 64);
    __syncthreads();
#pragma unroll
    for (int ks = 0; ks < 2; ++ks) {
      const int ch = ((ks * 4 + fq) ^ f7) << 3;     // swizzled 8-short chunk
      bf16x8 a[4], b[4];
#pragma unroll
      for (int i = 0; i < 4; ++i) {
        a[i] = *(const bf16x8*)&As[(wm * 64 + i * 16 + fr) * 64 + ch];
        b[i] = *(const bf16x8*)&Bs[(wn * 64 + i * 16 + fr) * 64 + ch];
      }
#pragma unroll
      for (int mt = 0; mt < 4; ++mt)
#pragma unroll
        for (int nt = 0; nt < 4; ++nt)
          acc[mt][nt] = __builtin_amdgcn_mfma_f32_16x16x32_bf16(a[mt], b[nt], acc[mt][nt], 0, 0, 0);
    }
  }

#pragma unroll
  for (int mt = 0; mt < 4; ++mt)
#pragma unroll
    for (int nt = 0; nt < 4; ++nt)
#pragma unroll
      for (int r = 0; r < 4; ++r) {
        int row = bm * 128 + wm * 64 + mt * 16 + fq * 4 + r;
        int col = bn * 128 + wn * 64 + nt * 16 + fr;
        float v = acc[mt][nt][r];
        if (bias) v += bias[col];
        if (flags & GF_GELU) v = gelu_f(v);
        if (flags & GF_RESID) v += resid[(size_t)row * N + col];
        if (flags & GF_SCALE) v *= scale[row];
        size_t idx = (size_t)row * N + col;
        if (C) { if (flags & GF_ACCUM) C[idx] += v; else C[idx] = v; }
        if (C2) C2[idx] = f2bf(v);
      }
}

// ---------------------------------------------------------------------------
// bf16 MFMA flash attention, causal, paired Q-tiles. Grid (16, B*H), 256 thr.
// Round-2: (a) T14 async staging — next tile's K/V global loads issue into
// registers during current tile's compute, LDS write happens after the
// barrier (hides ~900cyc HBM latency); (b) Vt XOR swizzle keyed on
// (d>>4)&3 — per-lane-varying on the write (4-way conflict -> 2-way/free),
// uniform XOR on the read.
// ---------------------------------------------------------------------------
__global__ __launch_bounds__(256) void attn_mfma(
    const unsigned short* __restrict__ qkv, unsigned short* __restrict__ o)
{
  __shared__ __align__(16) unsigned short Qs[64 * QS];
  __shared__ __align__(16) unsigned short Ks[64 * QS];
  __shared__ __align__(16) unsigned short Vt[64 * QS];  // transposed+swizzled
  __shared__ __align__(16) unsigned short Ps[64 * QS];  // wave-private 16-row bands

  const int tid  = threadIdx.x;
  const int wave = tid >> 6, lane = tid & 63;
  const int quad = lane >> 4, l15 = lane & 15;
  const int bh = blockIdx.y, b = bh >> 4, h = bh & 15;

  const int srow = tid >> 2;            // staging row 0..63
  const int scol = (tid & 3) << 4;      // staging col base (16 shorts)
  const int swcol = srow ^ ((tid & 3) << 3);  // swizzled k-index for Vt writes

  const unsigned short* kvb = qkv + (size_t)b * SEQ * 3072 + 1024 + h * 64 + scol;

  int4 ka, kb, va, vb;                  // prefetched K/V tile (registers)

  for (int half = 0; half < 2; ++half) {
    const int qb = half ? (31 - (int)blockIdx.x) : (int)blockIdx.x;
    const int q0 = qb << 6;

    __syncthreads();  // prior half fully done before overwriting Qs
    {
      const unsigned short* qp = qkv + ((size_t)(b * SEQ + q0 + srow)) * 3072 + h * 64 + scol;
      *(int4*)&Qs[srow * QS + scol]     = *(const int4*)qp;
      *(int4*)&Qs[srow * QS + scol + 8] = *(const int4*)(qp + 8);
    }
    {  // prefetch K/V tile 0 (overlaps Q barrier + fragment loads)
      const unsigned short* kp = kvb + (size_t)srow * 3072;
      ka = *(const int4*)kp;           kb = *(const int4*)(kp + 8);
      va = *(const int4*)(kp + 1024);  vb = *(const int4*)(kp + 1024 + 8);
    }
    __syncthreads();
    bf16x8 qf0 = *(const bf16x8*)&Qs[(wave * 16 + l15) * QS + quad * 8];
    bf16x8 qf1 = *(const bf16x8*)&Qs[(wave * 16 + l15) * QS + 32 + quad * 8];

    f32x4 Oc[4] = {};
    float mr[4] = {-1e30f, -1e30f, -1e30f, -1e30f};
    float ls[4] = {0.f, 0.f, 0.f, 0.f};

    for (int kt = 0; kt <= qb; ++kt) {
      __syncthreads();  // previous iteration's K/Vt reads complete
      {
        *(int4*)&Ks[srow * QS + scol]     = ka;
        *(int4*)&Ks[srow * QS + scol + 8] = kb;
        unsigned short vs[16];
        *(int4*)&vs[0] = va;
        *(int4*)&vs[8] = vb;
#pragma unroll
        for (int i = 0; i < 16; ++i)
          Vt[(scol + i) * QS + swcol] = vs[i];
      }
      if (kt < qb) {  // issue next tile's loads; results needed only after
        const unsigned short* kp = kvb + (size_t)((kt + 1) * 64 + srow) * 3072;
        ka = *(const int4*)kp;           kb = *(const int4*)(kp + 8);
        va = *(const int4*)(kp + 1024);  vb = *(const int4*)(kp + 1024 + 8);
      }
      __syncthreads();

      // S = Q K^T  (per wave: 16 rows x 64 cols = 4 col-tiles)
      f32x4 sc[4] = {};
#pragma unroll
      for (int ct = 0; ct < 4; ++ct) {
        bf16x8 k0 = *(const bf16x8*)&Ks[(ct * 16 + l15) * QS + quad * 8];
        bf16x8 k1 = *(const bf16x8*)&Ks[(ct * 16 + l15) * QS + 32 + quad * 8];
        sc[ct] = __builtin_amdgcn_mfma_f32_16x16x32_bf16(qf0, k0, sc[ct], 0, 0, 0);
        sc[ct] = __builtin_amdgcn_mfma_f32_16x16x32_bf16(qf1, k1, sc[ct], 0, 0, 0);
      }

      // scale + causal mask
      float sv[4][4];
      const bool diag = (kt == qb);
#pragma unroll
      for (int ct = 0; ct < 4; ++ct)
#pragma unroll
        for (int r = 0; r < 4; ++r) {
          float v = sc[ct][r] * 0.125f;
          if (diag && (ct * 16 + l15) > (wave * 16 + quad * 4 + r)) v = -1e9f;
          sv[ct][r] = v;
        }
      // row stats (rows live in one 16-lane group)
      float rm[4], rs[4];
#pragma unroll
      for (int r = 0; r < 4; ++r)
        rm[r] = fmaxf(fmaxf(sv[0][r], sv[1][r]), fmaxf(sv[2][r], sv[3][r]));
#pragma unroll
      for (int m = 1; m < 16; m <<= 1)
#pragma unroll
        for (int r = 0; r < 4; ++r) rm[r] = fmaxf(rm[r], __shfl_xor(rm[r], m, 16));
      float al[4];
#pragma unroll
      for (int r = 0; r < 4; ++r) {
        float nm = fmaxf(mr[r], rm[r]);
        al[r] = __expf(mr[r] - nm);
        mr[r] = nm;
        rs[r] = 0.f;
      }
#pragma unroll
      for (int ct = 0; ct < 4; ++ct)
#pragma unroll
        for (int r = 0; r < 4; ++r) {
          float p = __expf(sv[ct][r] - mr[r]);
          sv[ct][r] = p;
          rs[r] += p;
        }
#pragma unroll
      for (int m = 1; m < 16; m <<= 1)
#pragma unroll
        for (int r = 0; r < 4; ++r) rs[r] += __shfl_xor(rs[r], m, 16);
#pragma unroll
      for (int r = 0; r < 4; ++r) {
        ls[r] = ls[r] * al[r] + rs[r];
        for (int ct = 0; ct < 4; ++ct) Oc[ct][r] *= al[r];
      }
      // P -> LDS (wave-private band, no barrier needed)
#pragma unroll
      for (int ct = 0; ct < 4; ++ct)
#pragma unroll
        for (int r = 0; r < 4; ++r)
          Ps[(wave * 16 + quad * 4 + r) * QS + ct * 16 + l15] = f2bf(sv[ct][r]);
      // PV  (Vt reads: uniform XOR (quad^ct) selects swizzled chunk)
      bf16x8 pf0 = *(const bf16x8*)&Ps[(wave * 16 + l15) * QS + quad * 8];
      bf16x8 pf1 = *(const bf16x8*)&Ps[(wave * 16 + l15) * QS + 32 + quad * 8];
#pragma unroll
      for (int ct = 0; ct < 4; ++ct) {
        bf16x8 v0 = *(const bf16x8*)&Vt[(ct * 16 + l15) * QS + ((quad ^ ct) << 3)];
        bf16x8 v1 = *(const bf16x8*)&Vt[(ct * 16 + l15) * QS + 32 + ((quad ^ ct) << 3)];
        Oc[ct] = __builtin_amdgcn_mfma_f32_16x16x32_bf16(pf0, v0, Oc[ct], 0, 0, 0);
        Oc[ct] = __builtin_amdgcn_mfma_f32_16x16x32_bf16(pf1, v1, Oc[ct], 0, 0, 0);
      }
    }

#pragma unroll
    for (int r = 0; r < 4; ++r) {
      float inv = 1.0f / ls[r];
      unsigned short* orow = o + ((size_t)(b * SEQ + q0 + wave * 16 + quad * 4 + r)) * DIM + h * 64;
#pragma unroll
      for (int ct = 0; ct < 4; ++ct)
        orow[ct * 16 + l15] = f2bf(Oc[ct][r] * inv);
    }
  }
}

// ---------------------------------------------------------------------------
__global__ __launch_bounds__(256) void ln_kernel(
    const float* __restrict__ x, const float* __restrict__ g,
    const float* __restrict__ b, unsigned short* __restrict__ out)
{
  const int t = blockIdx.x, tid = threadIdx.x;
  const float* row = x + (size_t)t * DIM;
  float4 v = *(const float4*)(row + tid * 4);
  float s  = v.x + v.y + v.z + v.w;
  float s2 = v.x * v.x + v.y * v.y + v.z * v.z + v.w * v.w;
  for (int off = 1; off < 64; off <<= 1) {
    s  += __shfl_xor(s, off, 64);
    s2 += __shfl_xor(s2, off, 64);
  }
  __shared__ float red[8];
  const int wave = tid >> 6, lane = tid & 63;
  if (lane == 0) { red[wave] = s; red[4 + wave] = s2; }
  __syncthreads();
  float S  = red[0] + red[1] + red[2] + red[3];
  float S2 = red[4] + red[5] + red[6] + red[7];
  float mean = S * (1.0f / DIM);
  float var  = S2 * (1.0f / DIM) - mean * mean;
  float rstd = rsqrtf(var + 1e-5f);
  float4 gv = *(const float4*)(g + tid * 4);
  float4 bv = *(const float4*)(b + tid * 4);
  float ox = (v.x - mean) * rstd * gv.x + bv.x;
  float oy = (v.y - mean) * rstd * gv.y + bv.y;
  float oz = (v.z - mean) * rstd * gv.z + bv.z;
  float ow = (v.w - mean) * rstd * gv.w + bv.w;
  int2 pk; pk.x = pack2(ox, oy); pk.y = pack2(oz, ow);
  *(int2*)(out + (size_t)t * DIM + tid * 4) = pk;
}

// ---------------------------------------------------------------------------
// Router: per-token LN + 4-way gate logits + softmax + top-2. Atomic-free.
// ---------------------------------------------------------------------------
__global__ __launch_bounds__(128) void router_kernel(
    const float* __restrict__ xin, const float* __restrict__ g,
    const float* __restrict__ bb, const float* __restrict__ Wgp,
    float* __restrict__ stab, float* __restrict__ probs4, int* __restrict__ tops)
{
  const int t = blockIdx.x, tid = threadIdx.x;
  const float* row = xin + (size_t)t * DIM;
  float v[8]; float s = 0.f, s2 = 0.f;
#pragma unroll
  for (int k = 0; k < 8; ++k) {
    float u = row[tid + 128 * k];
    v[k] = u; s += u; s2 += u * u;
  }
  for (int off = 1; off < 64; off <<= 1) {
    s  += __shfl_xor(s, off, 64);
    s2 += __shfl_xor(s2, off, 64);
  }
  __shared__ float red[4];
  const int wv = tid >> 6, ln = tid & 63;
  if (ln == 0) { red[wv] = s; red[2 + wv] = s2; }
  __syncthreads();
  float S = red[0] + red[1], S2 = red[2] + red[3];
  float mean = S * (1.0f / DIM);
  float var  = S2 * (1.0f / DIM) - mean * mean;
  float rstd = rsqrtf(var + 1e-5f);
  float p0 = 0, p1 = 0, p2 = 0, p3 = 0;
#pragma unroll
  for (int k = 0; k < 8; ++k) {
    int i = tid + 128 * k;
    float hv = (v[k] - mean) * rstd * g[i] + bb[i];
    p0 += hv * Wgp[i];
    p1 += hv * Wgp[DIM + i];
    p2 += hv * Wgp[2 * DIM + i];
    p3 += hv * Wgp[3 * DIM + i];
  }
  __shared__ float sm[4][128];
  sm[0][tid] = p0; sm[1][tid] = p1; sm[2][tid] = p2; sm[3][tid] = p3;
  __syncthreads();
  for (int sft = 64; sft > 0; sft >>= 1) {
    if (tid < sft)
      for (int e = 0; e < 4; ++e) sm[e][tid] += sm[e][tid + sft];
    __syncthreads();
  }
  if (tid == 0) {
    float l[4] = { sm[0][0], sm[1][0], sm[2][0], sm[3][0] };
    float m = fmaxf(fmaxf(l[0], l[1]), fmaxf(l[2], l[3]));
    float pr[4]; float sum = 0.f;
    for (int e = 0; e < 4; ++e) { pr[e] = __expf(l[e] - m); sum += pr[e]; }
    for (int e = 0; e < 4; ++e) pr[e] /= sum;
    int i0 = 0;
    for (int e = 1; e < 4; ++e) if (pr[e] > pr[i0]) i0 = e;
    int i1 = -1;
    for (int e = 0; e < 4; ++e) if (e != i0 && (i1 < 0 || pr[e] > pr[i1])) i1 = e;
    float wsum = pr[i0] + pr[i1];
    for (int e = 0; e < 4; ++e)
      stab[(size_t)e * T_TOK + t] = (e == i0) ? pr[i0] / wsum : (e == i1) ? pr[i1] / wsum : 0.f;
    ((float4*)probs4)[t] = make_float4(pr[0], pr[1], pr[2], pr[3]);
    tops[t] = i0 | (i1 << 2);
  }
}

// Single-block reduction over per-token router outputs -> aux scalar.
__global__ __launch_bounds__(256) void moe_stats_kernel(
    const float* __restrict__ probs4, const int* __restrict__ tops,
    float* __restrict__ outaux)
{
  const int tid = threadIdx.x;
  float pi0 = 0, pi1 = 0, pi2 = 0, pi3 = 0;
  float fi0 = 0, fi1 = 0, fi2 = 0, fi3 = 0;
  for (int t = tid; t < T_TOK; t += 256) {
    float4 p = ((const float4*)probs4)[t];
    pi0 += p.x; pi1 += p.y; pi2 += p.z; pi3 += p.w;
    int ii = tops[t];
    int a = ii & 3, b = (ii >> 2) & 3;
    fi0 += (a == 0 ? 1.f : 0.f) + (b == 0 ? 1.f : 0.f);
    fi1 += (a == 1 ? 1.f : 0.f) + (b == 1 ? 1.f : 0.f);
    fi2 += (a == 2 ? 1.f : 0.f) + (b == 2 ? 1.f : 0.f);
    fi3 += (a == 3 ? 1.f : 0.f) + (b == 3 ? 1.f : 0.f);
  }
  for (int off = 1; off < 64; off <<= 1) {
    pi0 += __shfl_xor(pi0, off, 64); pi1 += __shfl_xor(pi1, off, 64);
    pi2 += __shfl_xor(pi2, off, 64); pi3 += __shfl_xor(pi3, off, 64);
    fi0 += __shfl_xor(fi0, off, 64); fi1 += __shfl_xor(fi1, off, 64);
    fi2 += __shfl_xor(fi2, off, 64); fi3 += __shfl_xor(fi3, off, 64);
  }
  __shared__ float red[8][4];
  const int wv = tid >> 6, ln = tid & 63;
  if (ln == 0) {
    red[0][wv] = pi0; red[1][wv] = pi1; red[2][wv] = pi2; red[3][wv] = pi3;
    red[4][wv] = fi0; red[5][wv] = fi1; red[6][wv] = fi2; red[7][wv] = fi3;
  }
  __syncthreads();
  if (tid == 0) {
    float P[4], F[4];
    for (int e = 0; e < 4; ++e) {
      P[e] = red[e][0] + red[e][1] + red[e][2] + red[e][3];
      F[e] = red[4 + e][0] + red[4 + e][1] + red[4 + e][2] + red[4 + e][3];
    }
    float sacc = F[0] * P[0] + F[1] * P[1] + F[2] * P[2] + F[3] * P[3];
    outaux[0] = 0.01f * 4.0f * sacc / (2.0f * (float)T_TOK * (float)T_TOK);
  }
}

// y = bs_dn + sum_e stab[e]*be_dn[e]; y2 = 0
__global__ __launch_bounds__(256) void init_y_kernel(
    const float* __restrict__ bs_dn, const float* __restrict__ be_dn,
    const float* __restrict__ stab, float* __restrict__ y, float* __restrict__ y2)
{
  const int t = blockIdx.x, c = threadIdx.x;
  float s0 = stab[t], s1 = stab[T_TOK + t], s2 = stab[2 * T_TOK + t], s3 = stab[3 * T_TOK + t];
  float4 acc = ((const float4*)bs_dn)[c];
  float4 b0 = ((const float4*)(be_dn + 0 * DIM))[c];
  float4 b1 = ((const float4*)(be_dn + 1 * DIM))[c];
  float4 b2 = ((const float4*)(be_dn + 2 * DIM))[c];
  float4 b3 = ((const float4*)(be_dn + 3 * DIM))[c];
  acc.x += s0 * b0.x + s1 * b1.x + s2 * b2.x + s3 * b3.x;
  acc.y += s0 * b0.y + s1 * b1.y + s2 * b2.y + s3 * b3.y;
  acc.z += s0 * b0.z + s1 * b1.z + s2 * b2.z + s3 * b3.z;
  acc.w += s0 * b0.w + s1 * b1.w + s2 * b2.w + s3 * b3.w;
  ((float4*)(y + (size_t)t * DIM))[c] = acc;
  ((float4*)(y2 + (size_t)t * DIM))[c] = make_float4(0.f, 0.f, 0.f, 0.f);
}

__global__ __launch_bounds__(256) void add3_kernel(
    const float* __restrict__ a, const float* __restrict__ b,
    const float* __restrict__ c, float* __restrict__ out, int n)
{
  int i = blockIdx.x * 256 + threadIdx.x;
  if (i < n) out[i] = a[i] + b[i] + c[i];
}

// ---------------------------------------------------------------------------
extern "C" void kernel_launch(void* const* d_in, const int* in_sizes, int n_in,
                              void* d_out, int out_size, void* d_ws, size_t ws_size,
                              hipStream_t stream)
{
  const float* x      = (const float*)d_in[0];
  const float* ln1_g  = (const float*)d_in[1];
  const float* ln1_b  = (const float*)d_in[2];
  const float* Wqkv   = (const float*)d_in[3];
  const float* bqkv   = (const float*)d_in[4];
  const float* Wo     = (const float*)d_in[5];
  const float* bo     = (const float*)d_in[6];
  const float* ln2_g  = (const float*)d_in[7];
  const float* ln2_b  = (const float*)d_in[8];
  const float* Wg     = (const float*)d_in[9];
  const float* We_up  = (const float*)d_in[10];
  const float* be_up  = (const float*)d_in[11];
  const float* We_dn  = (const float*)d_in[12];
  const float* be_dn  = (const float*)d_in[13];
  const float* Ws_up  = (const float*)d_in[14];
  const float* bs_up  = (const float*)d_in[15];
  const float* Ws_dn  = (const float*)d_in[16];
  const float* bs_dn  = (const float*)d_in[17];

  float* out = (float*)d_out;
  const size_t TD = (size_t)T_TOK * DIM;   // 4,194,304

  // Workspace: ~104 MB
  char* w = (char*)d_ws;
  float* x1 = (float*)w;  w += TD * 4;                          // 16 MB
  float* y  = (float*)w;                                        // 16 MB
  unsigned short* o_bf = (unsigned short*)y;                    //   (o dead before init_y)
  w += TD * 4;
  float* y2 = (float*)w;  w += TD * 4;                          // 16 MB
  unsigned short* pool = (unsigned short*)w;                    // 32 MB: qkv_bf then up_bf
  unsigned short* qkv_bf = pool;
  unsigned short* up_bf  = pool;
  w += (size_t)T_TOK * HIDD * 2;
  unsigned short* h_bf = (unsigned short*)w;  w += TD * 2;      // 8 MB
  unsigned short* P1   = (unsigned short*)w;  w += (size_t)HIDD * DIM * 2;  // 8 MB
  unsigned short* P2   = (unsigned short*)w;  w += (size_t)HIDD * DIM * 2;  // 8 MB
  float* stab = (float*)w;  w += (size_t)NEXP * T_TOK * 4;      // 64 KB
  float* probs4 = (float*)w; w += (size_t)T_TOK * 4 * 4;        // 64 KB
  int*   tops   = (int*)w;   w += (size_t)T_TOK * 4;            // 16 KB

  auto cvt = [&](const float* src, unsigned short* dst, int n) {
    cvt_kernel<<<(n / 8 + 255) / 256, 256, 0, stream>>>(src, dst, n / 8);
  };

  // 1) h = LN1(x) -> bf16 ; Wqkv -> P1
  cvt(Wqkv, P1, 3 * DIM * DIM);
  ln_kernel<<<T_TOK, 256, 0, stream>>>(x, ln1_g, ln1_b, h_bf);
  // 2) qkv (bf16 only)
  gemm_bf16<<<dim3(3072 / 128, T_TOK / 128), 256, 0, stream>>>(
      h_bf, P1, bqkv, nullptr, nullptr, nullptr, nullptr, qkv_bf, T_TOK, 3072, DIM, 0);
  // 3) o = causal MFMA attention -> bf16
  attn_mfma<<<dim3(16, 2 * NHEAD), 256, 0, stream>>>(qkv_bf, o_bf);
  // 4) x1 = x + o @ Wo^T + bo
  cvt(Wo, P2, DIM * DIM);
  gemm_bf16<<<dim3(DIM / 128, T_TOK / 128), 256, 0, stream>>>(
      o_bf, P2, bo, x, nullptr, x1, nullptr, nullptr, T_TOK, DIM, DIM, GF_RESID);
  // 5) h2 = LN2(x1) -> bf16
  ln_kernel<<<T_TOK, 256, 0, stream>>>(x1, ln2_g, ln2_b, h_bf);
  // 6) router (fp32 inline LN from x1), atomic-free; then single-block stats
  router_kernel<<<T_TOK, 128, 0, stream>>>(x1, ln2_g, ln2_b, Wg, stab, probs4, tops);
  moe_stats_kernel<<<1, 256, 0, stream>>>(probs4, tops, out);
  // 7) y/y2 init with all down-proj biases folded in
  init_y_kernel<<<T_TOK, 256, 0, stream>>>(bs_dn, be_dn, stab, y, y2);
  // 8) shared MLP: up (gelu) then split-K down accumulate
  cvt(Ws_up, P1, HIDD * DIM);
  gemm_bf16<<<dim3(HIDD / 128, T_TOK / 128), 256, 0, stream>>>(
      h_bf, P1, bs_up, nullptr, nullptr, nullptr, nullptr, up_bf, T_TOK, HIDD, DIM, GF_GELU);
  cvt(Ws_dn, P2, DIM * HIDD);
  gemm_bf16<<<dim3(DIM / 128, T_TOK / 128, 2), 256, 0, stream>>>(
      up_bf, P2, nullptr, nullptr, nullptr, y, y2, nullptr, T_TOK, DIM, HIDD, GF_ACCUM);
  // 9) MoE experts: scale folded into up epilogue; down pure accumulate
  for (int e = 0; e < NEXP; ++e) {
    cvt(We_up + (size_t)e * HIDD * DIM, P1, HIDD * DIM);
    gemm_bf16<<<dim3(HIDD / 128, T_TOK / 128), 256, 0, stream>>>(
        h_bf, P1, be_up + (size_t)e * HIDD,
        nullptr, stab + (size_t)e * T_TOK, nullptr, nullptr, up_bf,
        T_TOK, HIDD, DIM, GF_GELU | GF_SCALE);
    cvt(We_dn + (size_t)e * DIM * HIDD, P2, DIM * HIDD);
    gemm_bf16<<<dim3(DIM / 128, T_TOK / 128, 2), 256, 0, stream>>>(
        up_bf, P2, nullptr, nullptr, nullptr, y, y2, nullptr,
        T_TOK, DIM, HIDD, GF_ACCUM);
  }
  // 10) out = x1 + y + y2
  add3_kernel<<<(int)(TD / 256), 256, 0, stream>>>(x1, y, y2, out + 1, (int)TD);
}

// Round 4
// 1038.017 us; speedup vs baseline: 1.6258x; 1.1868x over previous
//
#include <hip/hip_runtime.h>
#include <hip/hip_bf16.h>

// Problem constants: B=2, S=2048, D=1024, H=16, HD=64, E=4, K=2, HID=4096, T=4096
#define T_TOK 4096
#define DIM   1024
#define NHEAD 16
#define HDIM  64
#define SEQ   2048
#define NEXP  4
#define HIDD  4096
#define QS    66   // attention LDS row stride (shorts)

typedef short bf16x8 __attribute__((ext_vector_type(8)));
typedef float f32x4  __attribute__((ext_vector_type(4)));

enum { GF_GELU = 1, GF_RESID = 2, GF_SCALE = 4, GF_ACCUM = 8 };

__device__ inline unsigned short f2bf(float f) {
  union { float f; unsigned u; } v; v.f = f;
  unsigned r = v.u + 0x7FFFu + ((v.u >> 16) & 1u);
  return (unsigned short)(r >> 16);
}
__device__ inline int pack2(float a, float b) {
  return (int)((unsigned)f2bf(a) | ((unsigned)f2bf(b) << 16));
}
// Fast tanh-approx GELU: gelu(x) = 0.5x(1+tanh(z)) = x - x/(1+e^{2z})
__device__ inline float gelu_f(float x) {
  float u = 1.5957691216057308f * x * (1.0f + 0.044715f * x * x);  // 2z
  float w = __expf(u);
  return x - x * __builtin_amdgcn_rcpf(w + 1.0f);
}
__device__ inline void gld_lds16(const unsigned short* g, unsigned short* l) {
  __builtin_amdgcn_global_load_lds(
      (const __attribute__((address_space(1))) void*)g,
      (__attribute__((address_space(3))) void*)l, 16, 0, 0);
}

// ---------------------------------------------------------------------------
__global__ __launch_bounds__(256) void cvt_kernel(
    const float* __restrict__ in, unsigned short* __restrict__ out, int n8)
{
  int i = blockIdx.x * 256 + threadIdx.x;
  if (i >= n8) return;
  const float4* p = (const float4*)in + (size_t)i * 2;
  float4 v0 = p[0], v1 = p[1];
  int4 pk = make_int4(pack2(v0.x, v0.y), pack2(v0.z, v0.w),
                      pack2(v1.x, v1.y), pack2(v1.z, v1.w));
  *(int4*)(out + (size_t)i * 8) = pk;
}

// ---------------------------------------------------------------------------
// Pipelined 256x256 bf16 GEMM: C2 = bf16(epilogue(A @ W^T + bias)).
// BK=64 split as two K-halves of 32. 8 waves (2M x 4N), 512 thr, 1 block/CU.
// LDS: 2 dbuf x 2 K-half x [256][32] for A and B = 128 KB.
// Swizzle: 16B chunk c' = c ^ (row&3) within each [256][32] region; staged
// via linear LDS dest + inverse-swizzled GLOBAL source (verified r3: 0 conf).
// Pipeline: counted vmcnt(4) gates at K-half boundaries only; next K-tile's
// half-tiles staged one per phase; vmcnt never drains to 0 in the main loop.
// ---------------------------------------------------------------------------
__global__ __launch_bounds__(512, 2) void gemm256(
    const unsigned short* __restrict__ A, const unsigned short* __restrict__ W,
    const float* __restrict__ bias, const float* __restrict__ scale,
    unsigned short* __restrict__ C2, int N, int Kd, int flags)
{
  __shared__ __align__(16) unsigned short Abuf[2][2][256 * 32];
  __shared__ __align__(16) unsigned short Bbuf[2][2][256 * 32];

  const int tid  = threadIdx.x;
  const int wave = tid >> 6, lane = tid & 63;

  // bijective XCD swizzle (nwg % 8 == 0 for all our launches)
  const int nwg  = gridDim.x * gridDim.y;
  const int flat = blockIdx.y * gridDim.x + blockIdx.x;
  const int swz  = (flat & 7) * (nwg >> 3) + (flat >> 3);
  const int bn = swz % gridDim.x, bm = swz / gridDim.x;

  // staging: per wave 32 rows of the 256-row tile; lane -> (row sr, chunk sc)
  const int sr = lane >> 2;                 // 0..15 row within 16-row slot
  const int sc = lane & 3;                  // 16B chunk within 64B row
  const int gcol = (sc ^ (sr & 3)) << 3;    // inverse-swizzled global col (shorts)
  const unsigned short* Ag = A + ((size_t)(bm * 256 + wave * 32 + sr)) * Kd + gcol;
  const unsigned short* Wg = W + ((size_t)(bn * 256 + wave * 32 + sr)) * Kd + gcol;

  const int wm = wave >> 2, wn = wave & 3;  // 2 x 4 wave grid
  const int fr = lane & 15, fq = lane >> 4;
  const int fx = (fq ^ (fr & 3)) << 3;      // swizzled chunk offset (shorts)

  f32x4 acc[8][4] = {};
  const int NT = Kd / 64;

  // stage K-tile 0: order [A-k0, B-k0, A-k1, B-k1], 2 gld_lds each
  {
    const unsigned short* a0 = Ag;
    const unsigned short* b0 = Wg;
    gld_lds16(a0,           &Abuf[0][0][(wave * 32) * 32]);
    gld_lds16(a0 + 16 * Kd, &Abuf[0][0][(wave * 32 + 16) * 32]);
    gld_lds16(b0,           &Bbuf[0][0][(wave * 32) * 32]);
    gld_lds16(b0 + 16 * Kd, &Bbuf[0][0][(wave * 32 + 16) * 32]);
    gld_lds16(a0 + 32,           &Abuf[0][1][(wave * 32) * 32]);
    gld_lds16(a0 + 32 + 16 * Kd, &Abuf[0][1][(wave * 32 + 16) * 32]);
    gld_lds16(b0 + 32,           &Bbuf[0][1][(wave * 32) * 32]);
    gld_lds16(b0 + 32 + 16 * Kd, &Bbuf[0][1][(wave * 32 + 16) * 32]);
  }

  for (int t = 0; t < NT; ++t) {
    const int buf = t & 1, nb = buf ^ 1;
    const bool more = (t + 1 < NT);
    const int nk0 = (t + 1) * 64;
    bf16x8 a[8], b0, b1;

    // ---- phase 0: kk=0, n-cols 0,1 -------------------------------------
    asm volatile("s_waitcnt vmcnt(4)" ::: "memory");
    __builtin_amdgcn_s_barrier();
#pragma unroll
    for (int m = 0; m < 8; ++m)
      a[m] = *(const bf16x8*)&Abuf[buf][0][(wm * 128 + m * 16 + fr) * 32 + fx];
    b0 = *(const bf16x8*)&Bbuf[buf][0][(wn * 64 +  0 + fr) * 32 + fx];
    b1 = *(const bf16x8*)&Bbuf[buf][0][(wn * 64 + 16 + fr) * 32 + fx];
    if (more) {
      const unsigned short* s0 = Ag + nk0;
      gld_lds16(s0,           &Abuf[nb][0][(wave * 32) * 32]);
      gld_lds16(s0 + 16 * Kd, &Abuf[nb][0][(wave * 32 + 16) * 32]);
    }
    __builtin_amdgcn_s_setprio(1);
#pragma unroll
    for (int m = 0; m < 8; ++m) {
      acc[m][0] = __builtin_amdgcn_mfma_f32_16x16x32_bf16(a[m], b0, acc[m][0], 0, 0, 0);
      acc[m][1] = __builtin_amdgcn_mfma_f32_16x16x32_bf16(a[m], b1, acc[m][1], 0, 0, 0);
    }
    __builtin_amdgcn_s_setprio(0);

    // ---- phase 1: kk=0, n-cols 2,3 -------------------------------------
    b0 = *(const bf16x8*)&Bbuf[buf][0][(wn * 64 + 32 + fr) * 32 + fx];
    b1 = *(const bf16x8*)&Bbuf[buf][0][(wn * 64 + 48 + fr) * 32 + fx];
    if (more) {
      const unsigned short* s0 = Wg + nk0;
      gld_lds16(s0,           &Bbuf[nb][0][(wave * 32) * 32]);
      gld_lds16(s0 + 16 * Kd, &Bbuf[nb][0][(wave * 32 + 16) * 32]);
    }
    __builtin_amdgcn_s_setprio(1);
#pragma unroll
    for (int m = 0; m < 8; ++m) {
      acc[m][2] = __builtin_amdgcn_mfma_f32_16x16x32_bf16(a[m], b0, acc[m][2], 0, 0, 0);
      acc[m][3] = __builtin_amdgcn_mfma_f32_16x16x32_bf16(a[m], b1, acc[m][3], 0, 0, 0);
    }
    __builtin_amdgcn_s_setprio(0);

    // ---- phase 2: kk=1, n-cols 0,1 -------------------------------------
    asm volatile("s_waitcnt vmcnt(4)" ::: "memory");
    __builtin_amdgcn_s_barrier();
#pragma unroll
    for (int m = 0; m < 8; ++m)
      a[m] = *(const bf16x8*)&Abuf[buf][1][(wm * 128 + m * 16 + fr) * 32 + fx];
    b0 = *(const bf16x8*)&Bbuf[buf][1][(wn * 64 +  0 + fr) * 32 + fx];
    b1 = *(const bf16x8*)&Bbuf[buf][1][(wn * 64 + 16 + fr) * 32 + fx];
    if (more) {
      const unsigned short* s0 = Ag + nk0 + 32;
      gld_lds16(s0,           &Abuf[nb][1][(wave * 32) * 32]);
      gld_lds16(s0 + 16 * Kd, &Abuf[nb][1][(wave * 32 + 16) * 32]);
    }
    __builtin_amdgcn_s_setprio(1);
#pragma unroll
    for (int m = 0; m < 8; ++m) {
      acc[m][0] = __builtin_amdgcn_mfma_f32_16x16x32_bf16(a[m], b0, acc[m][0], 0, 0, 0);
      acc[m][1] = __builtin_amdgcn_mfma_f32_16x16x32_bf16(a[m], b1, acc[m][1], 0, 0, 0);
    }
    __builtin_amdgcn_s_setprio(0);

    // ---- phase 3: kk=1, n-cols 2,3 -------------------------------------
    b0 = *(const bf16x8*)&Bbuf[buf][1][(wn * 64 + 32 + fr) * 32 + fx];
    b1 = *(const bf16x8*)&Bbuf[buf][1][(wn * 64 + 48 + fr) * 32 + fx];
    if (more) {
      const unsigned short* s0 = Wg + nk0 + 32;
      gld_lds16(s0,           &Bbuf[nb][1][(wave * 32) * 32]);
      gld_lds16(s0 + 16 * Kd, &Bbuf[nb][1][(wave * 32 + 16) * 32]);
    }
    __builtin_amdgcn_s_setprio(1);
#pragma unroll
    for (int m = 0; m < 8; ++m) {
      acc[m][2] = __builtin_amdgcn_mfma_f32_16x16x32_bf16(a[m], b0, acc[m][2], 0, 0, 0);
      acc[m][3] = __builtin_amdgcn_mfma_f32_16x16x32_bf16(a[m], b1, acc[m][3], 0, 0, 0);
    }
    __builtin_amdgcn_s_setprio(0);
  }

#pragma unroll
  for (int m = 0; m < 8; ++m)
#pragma unroll
    for (int n = 0; n < 4; ++n)
#pragma unroll
      for (int r = 0; r < 4; ++r) {
        int row = bm * 256 + wm * 128 + m * 16 + fq * 4 + r;
        int col = bn * 256 + wn * 64 + n * 16 + fr;
        float v = acc[m][n][r] + bias[col];
        if (flags & GF_GELU) v = gelu_f(v);
        if (flags & GF_SCALE) v *= scale[row];
        C2[(size_t)row * N + col] = f2bf(v);
      }
}

// ---------------------------------------------------------------------------
// bf16 GEMM: C = A @ W^T (+epilogue). 128x128 tile, BK=64, 256 thr.
// (retained for Wo and the split-K down projections)
// ---------------------------------------------------------------------------
__global__ __launch_bounds__(256) void gemm_bf16(
    const unsigned short* __restrict__ A, const unsigned short* __restrict__ W,
    const float* __restrict__ bias, const float* __restrict__ resid,
    const float* __restrict__ scale, float* __restrict__ C,
    float* __restrict__ Cz, unsigned short* __restrict__ C2,
    int M, int N, int Kd, int flags)
{
  __shared__ __align__(16) unsigned short As[128 * 64];
  __shared__ __align__(16) unsigned short Bs[128 * 64];

  const int tid  = threadIdx.x;
  const int wave = tid >> 6, lane = tid & 63;
  const int bm = blockIdx.y, bn = blockIdx.x;
  const int kz = blockIdx.z;
  const int kseg = Kd / gridDim.z;       // K-range for this z-slice
  if (kz == 1) C = Cz;

  const int srow = lane >> 3;                       // 0..7
  const int scol = ((lane & 7) ^ srow) << 3;        // inverse-swizzled source chunk
  const unsigned short* Ag = A + (size_t)(bm * 128 + wave * 32 + srow) * Kd + scol + (size_t)kz * kseg;
  const unsigned short* Wg = W + (size_t)(bn * 128 + wave * 32 + srow) * Kd + scol + (size_t)kz * kseg;
  unsigned short* AsBase = As + wave * 32 * 64;
  unsigned short* BsBase = Bs + wave * 32 * 64;

  const int wm = wave >> 1, wn = wave & 1;
  const int fr = lane & 15;
  const int fq = lane >> 4;
  const int f7 = fr & 7;

  f32x4 acc[4][4] = {};

  for (int k0 = 0; k0 < kseg; k0 += 64) {
    __syncthreads();
    gld_lds16(Ag + k0,            AsBase);
    gld_lds16(Ag + k0 +  8 * Kd,  AsBase +  8 * 64);
    gld_lds16(Ag + k0 + 16 * Kd,  AsBase + 16 * 64);
    gld_lds16(Ag + k0 + 24 * Kd,  AsBase + 24 * 64);
    gld_lds16(Wg + k0,            BsBase);
    gld_lds16(Wg + k0 +  8 * Kd,  BsBase +  8 * 64);
    gld_lds16(Wg + k0 + 16 * Kd,  BsBase + 16 * 64);
    gld_lds16(Wg + k0 + 24 * Kd,  BsBase + 24 * 64);
    __syncthreads();
#pragma unroll
    for (int ks = 0; ks < 2; ++ks) {
      const int ch = ((ks * 4 + fq) ^ f7) << 3;     // swizzled 8-short chunk
      bf16x8 a[4], b[4];
#pragma unroll
      for (int i = 0; i < 4; ++i) {
        a[i] = *(const bf16x8*)&As[(wm * 64 + i * 16 + fr) * 64 + ch];
        b[i] = *(const bf16x8*)&Bs[(wn * 64 + i * 16 + fr) * 64 + ch];
      }
#pragma unroll
      for (int mt = 0; mt < 4; ++mt)
#pragma unroll
        for (int nt = 0; nt < 4; ++nt)
          acc[mt][nt] = __builtin_amdgcn_mfma_f32_16x16x32_bf16(a[mt], b[nt], acc[mt][nt], 0, 0, 0);
    }
  }

#pragma unroll
  for (int mt = 0; mt < 4; ++mt)
#pragma unroll
    for (int nt = 0; nt < 4; ++nt)
#pragma unroll
      for (int r = 0; r < 4; ++r) {
        int row = bm * 128 + wm * 64 + mt * 16 + fq * 4 + r;
        int col = bn * 128 + wn * 64 + nt * 16 + fr;
        float v = acc[mt][nt][r];
        if (bias) v += bias[col];
        if (flags & GF_GELU) v = gelu_f(v);
        if (flags & GF_RESID) v += resid[(size_t)row * N + col];
        if (flags & GF_SCALE) v *= scale[row];
        size_t idx = (size_t)row * N + col;
        if (C) { if (flags & GF_ACCUM) C[idx] += v; else C[idx] = v; }
        if (C2) C2[idx] = f2bf(v);
      }
}

// ---------------------------------------------------------------------------
// bf16 MFMA flash attention, causal, paired Q-tiles. Grid (16, B*H), 256 thr.
// T14 async staging + swizzled Vt (round 2).
// ---------------------------------------------------------------------------
__global__ __launch_bounds__(256) void attn_mfma(
    const unsigned short* __restrict__ qkv, unsigned short* __restrict__ o)
{
  __shared__ __align__(16) unsigned short Qs[64 * QS];
  __shared__ __align__(16) unsigned short Ks[64 * QS];
  __shared__ __align__(16) unsigned short Vt[64 * QS];  // transposed+swizzled
  __shared__ __align__(16) unsigned short Ps[64 * QS];  // wave-private 16-row bands

  const int tid  = threadIdx.x;
  const int wave = tid >> 6, lane = tid & 63;
  const int quad = lane >> 4, l15 = lane & 15;
  const int bh = blockIdx.y, b = bh >> 4, h = bh & 15;

  const int srow = tid >> 2;            // staging row 0..63
  const int scol = (tid & 3) << 4;      // staging col base (16 shorts)
  const int swcol = srow ^ ((tid & 3) << 3);  // swizzled k-index for Vt writes

  const unsigned short* kvb = qkv + (size_t)b * SEQ * 3072 + 1024 + h * 64 + scol;

  int4 ka, kb, va, vb;                  // prefetched K/V tile (registers)

  for (int half = 0; half < 2; ++half) {
    const int qb = half ? (31 - (int)blockIdx.x) : (int)blockIdx.x;
    const int q0 = qb << 6;

    __syncthreads();  // prior half fully done before overwriting Qs
    {
      const unsigned short* qp = qkv + ((size_t)(b * SEQ + q0 + srow)) * 3072 + h * 64 + scol;
      *(int4*)&Qs[srow * QS + scol]     = *(const int4*)qp;
      *(int4*)&Qs[srow * QS + scol + 8] = *(const int4*)(qp + 8);
    }
    {  // prefetch K/V tile 0
      const unsigned short* kp = kvb + (size_t)srow * 3072;
      ka = *(const int4*)kp;           kb = *(const int4*)(kp + 8);
      va = *(const int4*)(kp + 1024);  vb = *(const int4*)(kp + 1024 + 8);
    }
    __syncthreads();
    bf16x8 qf0 = *(const bf16x8*)&Qs[(wave * 16 + l15) * QS + quad * 8];
    bf16x8 qf1 = *(const bf16x8*)&Qs[(wave * 16 + l15) * QS + 32 + quad * 8];

    f32x4 Oc[4] = {};
    float mr[4] = {-1e30f, -1e30f, -1e30f, -1e30f};
    float ls[4] = {0.f, 0.f, 0.f, 0.f};

    for (int kt = 0; kt <= qb; ++kt) {
      __syncthreads();  // previous iteration's K/Vt reads complete
      {
        *(int4*)&Ks[srow * QS + scol]     = ka;
        *(int4*)&Ks[srow * QS + scol + 8] = kb;
        unsigned short vs[16];
        *(int4*)&vs[0] = va;
        *(int4*)&vs[8] = vb;
#pragma unroll
        for (int i = 0; i < 16; ++i)
          Vt[(scol + i) * QS + swcol] = vs[i];
      }
      if (kt < qb) {  // issue next tile's loads
        const unsigned short* kp = kvb + (size_t)((kt + 1) * 64 + srow) * 3072;
        ka = *(const int4*)kp;           kb = *(const int4*)(kp + 8);
        va = *(const int4*)(kp + 1024);  vb = *(const int4*)(kp + 1024 + 8);
      }
      __syncthreads();

      // S = Q K^T  (per wave: 16 rows x 64 cols = 4 col-tiles)
      f32x4 sc[4] = {};
#pragma unroll
      for (int ct = 0; ct < 4; ++ct) {
        bf16x8 k0 = *(const bf16x8*)&Ks[(ct * 16 + l15) * QS + quad * 8];
        bf16x8 k1 = *(const bf16x8*)&Ks[(ct * 16 + l15) * QS + 32 + quad * 8];
        sc[ct] = __builtin_amdgcn_mfma_f32_16x16x32_bf16(qf0, k0, sc[ct], 0, 0, 0);
        sc[ct] = __builtin_amdgcn_mfma_f32_16x16x32_bf16(qf1, k1, sc[ct], 0, 0, 0);
      }

      // scale + causal mask
      float sv[4][4];
      const bool diag = (kt == qb);
#pragma unroll
      for (int ct = 0; ct < 4; ++ct)
#pragma unroll
        for (int r = 0; r < 4; ++r) {
          float v = sc[ct][r] * 0.125f;
          if (diag && (ct * 16 + l15) > (wave * 16 + quad * 4 + r)) v = -1e9f;
          sv[ct][r] = v;
        }
      float rm[4], rs[4];
#pragma unroll
      for (int r = 0; r < 4; ++r)
        rm[r] = fmaxf(fmaxf(sv[0][r], sv[1][r]), fmaxf(sv[2][r], sv[3][r]));
#pragma unroll
      for (int m = 1; m < 16; m <<= 1)
#pragma unroll
        for (int r = 0; r < 4; ++r) rm[r] = fmaxf(rm[r], __shfl_xor(rm[r], m, 16));
      float al[4];
#pragma unroll
      for (int r = 0; r < 4; ++r) {
        float nm = fmaxf(mr[r], rm[r]);
        al[r] = __expf(mr[r] - nm);
        mr[r] = nm;
        rs[r] = 0.f;
      }
#pragma unroll
      for (int ct = 0; ct < 4; ++ct)
#pragma unroll
        for (int r = 0; r < 4; ++r) {
          float p = __expf(sv[ct][r] - mr[r]);
          sv[ct][r] = p;
          rs[r] += p;
        }
#pragma unroll
      for (int m = 1; m < 16; m <<= 1)
#pragma unroll
        for (int r = 0; r < 4; ++r) rs[r] += __shfl_xor(rs[r], m, 16);
#pragma unroll
      for (int r = 0; r < 4; ++r) {
        ls[r] = ls[r] * al[r] + rs[r];
        for (int ct = 0; ct < 4; ++ct) Oc[ct][r] *= al[r];
      }
      // P -> LDS (wave-private band)
#pragma unroll
      for (int ct = 0; ct < 4; ++ct)
#pragma unroll
        for (int r = 0; r < 4; ++r)
          Ps[(wave * 16 + quad * 4 + r) * QS + ct * 16 + l15] = f2bf(sv[ct][r]);
      // PV
      bf16x8 pf0 = *(const bf16x8*)&Ps[(wave * 16 + l15) * QS + quad * 8];
      bf16x8 pf1 = *(const bf16x8*)&Ps[(wave * 16 + l15) * QS + 32 + quad * 8];
#pragma unroll
      for (int ct = 0; ct < 4; ++ct) {
        bf16x8 v0 = *(const bf16x8*)&Vt[(ct * 16 + l15) * QS + ((quad ^ ct) << 3)];
        bf16x8 v1 = *(const bf16x8*)&Vt[(ct * 16 + l15) * QS + 32 + ((quad ^ ct) << 3)];
        Oc[ct] = __builtin_amdgcn_mfma_f32_16x16x32_bf16(pf0, v0, Oc[ct], 0, 0, 0);
        Oc[ct] = __builtin_amdgcn_mfma_f32_16x16x32_bf16(pf1, v1, Oc[ct], 0, 0, 0);
      }
    }

#pragma unroll
    for (int r = 0; r < 4; ++r) {
      float inv = 1.0f / ls[r];
      unsigned short* orow = o + ((size_t)(b * SEQ + q0 + wave * 16 + quad * 4 + r)) * DIM + h * 64;
#pragma unroll
      for (int ct = 0; ct < 4; ++ct)
        orow[ct * 16 + l15] = f2bf(Oc[ct][r] * inv);
    }
  }
}

// ---------------------------------------------------------------------------
__global__ __launch_bounds__(256) void ln_kernel(
    const float* __restrict__ x, const float* __restrict__ g,
    const float* __restrict__ b, unsigned short* __restrict__ out)
{
  const int t = blockIdx.x, tid = threadIdx.x;
  const float* row = x + (size_t)t * DIM;
  float4 v = *(const float4*)(row + tid * 4);
  float s  = v.x + v.y + v.z + v.w;
  float s2 = v.x * v.x + v.y * v.y + v.z * v.z + v.w * v.w;
  for (int off = 1; off < 64; off <<= 1) {
    s  += __shfl_xor(s, off, 64);
    s2 += __shfl_xor(s2, off, 64);
  }
  __shared__ float red[8];
  const int wave = tid >> 6, lane = tid & 63;
  if (lane == 0) { red[wave] = s; red[4 + wave] = s2; }
  __syncthreads();
  float S  = red[0] + red[1] + red[2] + red[3];
  float S2 = red[4] + red[5] + red[6] + red[7];
  float mean = S * (1.0f / DIM);
  float var  = S2 * (1.0f / DIM) - mean * mean;
  float rstd = rsqrtf(var + 1e-5f);
  float4 gv = *(const float4*)(g + tid * 4);
  float4 bv = *(const float4*)(b + tid * 4);
  float ox = (v.x - mean) * rstd * gv.x + bv.x;
  float oy = (v.y - mean) * rstd * gv.y + bv.y;
  float oz = (v.z - mean) * rstd * gv.z + bv.z;
  float ow = (v.w - mean) * rstd * gv.w + bv.w;
  int2 pk; pk.x = pack2(ox, oy); pk.y = pack2(oz, ow);
  *(int2*)(out + (size_t)t * DIM + tid * 4) = pk;
}

// ---------------------------------------------------------------------------
// Router: per-token LN + 4-way gate logits + softmax + top-2. Atomic-free.
// ---------------------------------------------------------------------------
__global__ __launch_bounds__(128) void router_kernel(
    const float* __restrict__ xin, const float* __restrict__ g,
    const float* __restrict__ bb, const float* __restrict__ Wgp,
    float* __restrict__ stab, float* __restrict__ probs4, int* __restrict__ tops)
{
  const int t = blockIdx.x, tid = threadIdx.x;
  const float* row = xin + (size_t)t * DIM;
  float v[8]; float s = 0.f, s2 = 0.f;
#pragma unroll
  for (int k = 0; k < 8; ++k) {
    float u = row[tid + 128 * k];
    v[k] = u; s += u; s2 += u * u;
  }
  for (int off = 1; off < 64; off <<= 1) {
    s  += __shfl_xor(s, off, 64);
    s2 += __shfl_xor(s2, off, 64);
  }
  __shared__ float red[4];
  const int wv = tid >> 6, ln = tid & 63;
  if (ln == 0) { red[wv] = s; red[2 + wv] = s2; }
  __syncthreads();
  float S = red[0] + red[1], S2 = red[2] + red[3];
  float mean = S * (1.0f / DIM);
  float var  = S2 * (1.0f / DIM) - mean * mean;
  float rstd = rsqrtf(var + 1e-5f);
  float p0 = 0, p1 = 0, p2 = 0, p3 = 0;
#pragma unroll
  for (int k = 0; k < 8; ++k) {
    int i = tid + 128 * k;
    float hv = (v[k] - mean) * rstd * g[i] + bb[i];
    p0 += hv * Wgp[i];
    p1 += hv * Wgp[DIM + i];
    p2 += hv * Wgp[2 * DIM + i];
    p3 += hv * Wgp[3 * DIM + i];
  }
  __shared__ float sm[4][128];
  sm[0][tid] = p0; sm[1][tid] = p1; sm[2][tid] = p2; sm[3][tid] = p3;
  __syncthreads();
  for (int sft = 64; sft > 0; sft >>= 1) {
    if (tid < sft)
      for (int e = 0; e < 4; ++e) sm[e][tid] += sm[e][tid + sft];
    __syncthreads();
  }
  if (tid == 0) {
    float l[4] = { sm[0][0], sm[1][0], sm[2][0], sm[3][0] };
    float m = fmaxf(fmaxf(l[0], l[1]), fmaxf(l[2], l[3]));
    float pr[4]; float sum = 0.f;
    for (int e = 0; e < 4; ++e) { pr[e] = __expf(l[e] - m); sum += pr[e]; }
    for (int e = 0; e < 4; ++e) pr[e] /= sum;
    int i0 = 0;
    for (int e = 1; e < 4; ++e) if (pr[e] > pr[i0]) i0 = e;
    int i1 = -1;
    for (int e = 0; e < 4; ++e) if (e != i0 && (i1 < 0 || pr[e] > pr[i1])) i1 = e;
    float wsum = pr[i0] + pr[i1];
    for (int e = 0; e < 4; ++e)
      stab[(size_t)e * T_TOK + t] = (e == i0) ? pr[i0] / wsum : (e == i1) ? pr[i1] / wsum : 0.f;
    ((float4*)probs4)[t] = make_float4(pr[0], pr[1], pr[2], pr[3]);
    tops[t] = i0 | (i1 << 2);
  }
}

// Single-block reduction over per-token router outputs -> aux scalar.
__global__ __launch_bounds__(256) void moe_stats_kernel(
    const float* __restrict__ probs4, const int* __restrict__ tops,
    float* __restrict__ outaux)
{
  const int tid = threadIdx.x;
  float pi0 = 0, pi1 = 0, pi2 = 0, pi3 = 0;
  float fi0 = 0, fi1 = 0, fi2 = 0, fi3 = 0;
  for (int t = tid; t < T_TOK; t += 256) {
    float4 p = ((const float4*)probs4)[t];
    pi0 += p.x; pi1 += p.y; pi2 += p.z; pi3 += p.w;
    int ii = tops[t];
    int a = ii & 3, b = (ii >> 2) & 3;
    fi0 += (a == 0 ? 1.f : 0.f) + (b == 0 ? 1.f : 0.f);
    fi1 += (a == 1 ? 1.f : 0.f) + (b == 1 ? 1.f : 0.f);
    fi2 += (a == 2 ? 1.f : 0.f) + (b == 2 ? 1.f : 0.f);
    fi3 += (a == 3 ? 1.f : 0.f) + (b == 3 ? 1.f : 0.f);
  }
  for (int off = 1; off < 64; off <<= 1) {
    pi0 += __shfl_xor(pi0, off, 64); pi1 += __shfl_xor(pi1, off, 64);
    pi2 += __shfl_xor(pi2, off, 64); pi3 += __shfl_xor(pi3, off, 64);
    fi0 += __shfl_xor(fi0, off, 64); fi1 += __shfl_xor(fi1, off, 64);
    fi2 += __shfl_xor(fi2, off, 64); fi3 += __shfl_xor(fi3, off, 64);
  }
  __shared__ float red[8][4];
  const int wv = tid >> 6, ln = tid & 63;
  if (ln == 0) {
    red[0][wv] = pi0; red[1][wv] = pi1; red[2][wv] = pi2; red[3][wv] = pi3;
    red[4][wv] = fi0; red[5][wv] = fi1; red[6][wv] = fi2; red[7][wv] = fi3;
  }
  __syncthreads();
  if (tid == 0) {
    float P[4], F[4];
    for (int e = 0; e < 4; ++e) {
      P[e] = red[e][0] + red[e][1] + red[e][2] + red[e][3];
      F[e] = red[4 + e][0] + red[4 + e][1] + red[4 + e][2] + red[4 + e][3];
    }
    float sacc = F[0] * P[0] + F[1] * P[1] + F[2] * P[2] + F[3] * P[3];
    outaux[0] = 0.01f * 4.0f * sacc / (2.0f * (float)T_TOK * (float)T_TOK);
  }
}

// y = bs_dn + sum_e stab[e]*be_dn[e]; y2 = 0
__global__ __launch_bounds__(256) void init_y_kernel(
    const float* __restrict__ bs_dn, const float* __restrict__ be_dn,
    const float* __restrict__ stab, float* __restrict__ y, float* __restrict__ y2)
{
  const int t = blockIdx.x, c = threadIdx.x;
  float s0 = stab[t], s1 = stab[T_TOK + t], s2 = stab[2 * T_TOK + t], s3 = stab[3 * T_TOK + t];
  float4 acc = ((const float4*)bs_dn)[c];
  float4 b0 = ((const float4*)(be_dn + 0 * DIM))[c];
  float4 b1 = ((const float4*)(be_dn + 1 * DIM))[c];
  float4 b2 = ((const float4*)(be_dn + 2 * DIM))[c];
  float4 b3 = ((const float4*)(be_dn + 3 * DIM))[c];
  acc.x += s0 * b0.x + s1 * b1.x + s2 * b2.x + s3 * b3.x;
  acc.y += s0 * b0.y + s1 * b1.y + s2 * b2.y + s3 * b3.y;
  acc.z += s0 * b0.z + s1 * b1.z + s2 * b2.z + s3 * b3.z;
  acc.w += s0 * b0.w + s1 * b1.w + s2 * b2.w + s3 * b3.w;
  ((float4*)(y + (size_t)t * DIM))[c] = acc;
  ((float4*)(y2 + (size_t)t * DIM))[c] = make_float4(0.f, 0.f, 0.f, 0.f);
}

__global__ __launch_bounds__(256) void add3_kernel(
    const float* __restrict__ a, const float* __restrict__ b,
    const float* __restrict__ c, float* __restrict__ out, int n)
{
  int i = blockIdx.x * 256 + threadIdx.x;
  if (i < n) out[i] = a[i] + b[i] + c[i];
}

// ---------------------------------------------------------------------------
extern "C" void kernel_launch(void* const* d_in, const int* in_sizes, int n_in,
                              void* d_out, int out_size, void* d_ws, size_t ws_size,
                              hipStream_t stream)
{
  const float* x      = (const float*)d_in[0];
  const float* ln1_g  = (const float*)d_in[1];
  const float* ln1_b  = (const float*)d_in[2];
  const float* Wqkv   = (const float*)d_in[3];
  const float* bqkv   = (const float*)d_in[4];
  const float* Wo     = (const float*)d_in[5];
  const float* bo     = (const float*)d_in[6];
  const float* ln2_g  = (const float*)d_in[7];
  const float* ln2_b  = (const float*)d_in[8];
  const float* Wg     = (const float*)d_in[9];
  const float* We_up  = (const float*)d_in[10];
  const float* be_up  = (const float*)d_in[11];
  const float* We_dn  = (const float*)d_in[12];
  const float* be_dn  = (const float*)d_in[13];
  const float* Ws_up  = (const float*)d_in[14];
  const float* bs_up  = (const float*)d_in[15];
  const float* Ws_dn  = (const float*)d_in[16];
  const float* bs_dn  = (const float*)d_in[17];

  float* out = (float*)d_out;
  const size_t TD = (size_t)T_TOK * DIM;   // 4,194,304

  // Workspace: ~104 MB
  char* w = (char*)d_ws;
  float* x1 = (float*)w;  w += TD * 4;                          // 16 MB
  float* y  = (float*)w;                                        // 16 MB
  unsigned short* o_bf = (unsigned short*)y;                    //   (o dead before init_y)
  w += TD * 4;
  float* y2 = (float*)w;  w += TD * 4;                          // 16 MB
  unsigned short* pool = (unsigned short*)w;                    // 32 MB: qkv_bf then up_bf
  unsigned short* qkv_bf = pool;
  unsigned short* up_bf  = pool;
  w += (size_t)T_TOK * HIDD * 2;
  unsigned short* h_bf = (unsigned short*)w;  w += TD * 2;      // 8 MB
  unsigned short* P1   = (unsigned short*)w;  w += (size_t)HIDD * DIM * 2;  // 8 MB
  unsigned short* P2   = (unsigned short*)w;  w += (size_t)HIDD * DIM * 2;  // 8 MB
  float* stab = (float*)w;  w += (size_t)NEXP * T_TOK * 4;      // 64 KB
  float* probs4 = (float*)w; w += (size_t)T_TOK * 4 * 4;        // 64 KB
  int*   tops   = (int*)w;   w += (size_t)T_TOK * 4;            // 16 KB

  auto cvt = [&](const float* src, unsigned short* dst, int n) {
    cvt_kernel<<<(n / 8 + 255) / 256, 256, 0, stream>>>(src, dst, n / 8);
  };

  // 1) h = LN1(x) -> bf16 ; Wqkv -> P1
  cvt(Wqkv, P1, 3 * DIM * DIM);
  ln_kernel<<<T_TOK, 256, 0, stream>>>(x, ln1_g, ln1_b, h_bf);
  // 2) qkv (bf16 only) -- pipelined 256^2 kernel
  gemm256<<<dim3(3072 / 256, T_TOK / 256), 512, 0, stream>>>(
      h_bf, P1, bqkv, nullptr, qkv_bf, 3072, DIM, 0);
  // 3) o = causal MFMA attention -> bf16
  attn_mfma<<<dim3(16, 2 * NHEAD), 256, 0, stream>>>(qkv_bf, o_bf);
  // 4) x1 = x + o @ Wo^T + bo
  cvt(Wo, P2, DIM * DIM);
  gemm_bf16<<<dim3(DIM / 128, T_TOK / 128), 256, 0, stream>>>(
      o_bf, P2, bo, x, nullptr, x1, nullptr, nullptr, T_TOK, DIM, DIM, GF_RESID);
  // 5) h2 = LN2(x1) -> bf16
  ln_kernel<<<T_TOK, 256, 0, stream>>>(x1, ln2_g, ln2_b, h_bf);
  // 6) router (fp32 inline LN from x1), atomic-free; then single-block stats
  router_kernel<<<T_TOK, 128, 0, stream>>>(x1, ln2_g, ln2_b, Wg, stab, probs4, tops);
  moe_stats_kernel<<<1, 256, 0, stream>>>(probs4, tops, out);
  // 7) y/y2 init with all down-proj biases folded in
  init_y_kernel<<<T_TOK, 256, 0, stream>>>(bs_dn, be_dn, stab, y, y2);
  // 8) shared MLP: up (gelu, pipelined) then split-K down accumulate
  cvt(Ws_up, P1, HIDD * DIM);
  gemm256<<<dim3(HIDD / 256, T_TOK / 256), 512, 0, stream>>>(
      h_bf, P1, bs_up, nullptr, up_bf, HIDD, DIM, GF_GELU);
  cvt(Ws_dn, P2, DIM * HIDD);
  gemm_bf16<<<dim3(DIM / 128, T_TOK / 128, 2), 256, 0, stream>>>(
      up_bf, P2, nullptr, nullptr, nullptr, y, y2, nullptr, T_TOK, DIM, HIDD, GF_ACCUM);
  // 9) MoE experts: scale folded into up epilogue; down pure accumulate
  for (int e = 0; e < NEXP; ++e) {
    cvt(We_up + (size_t)e * HIDD * DIM, P1, HIDD * DIM);
    gemm256<<<dim3(HIDD / 256, T_TOK / 256), 512, 0, stream>>>(
        h_bf, P1, be_up + (size_t)e * HIDD, stab + (size_t)e * T_TOK, up_bf,
        HIDD, DIM, GF_GELU | GF_SCALE);
    cvt(We_dn + (size_t)e * DIM * HIDD, P2, DIM * HIDD);
    gemm_bf16<<<dim3(DIM / 128, T_TOK / 128, 2), 256, 0, stream>>>(
        up_bf, P2, nullptr, nullptr, nullptr, y, y2, nullptr,
        T_TOK, DIM, HIDD, GF_ACCUM);
  }
  // 10) out = x1 + y + y2
  add3_kernel<<<(int)(TD / 256), 256, 0, stream>>>(x1, y, y2, out + 1, (int)TD);
}